// Round 16
// baseline (59.833 us; speedup 1.0000x reference)
//
#include <hip/hip_runtime.h>

// Problem constants (reference: B=16, Q=2048, K=2048, D=128, fp32, NEG=-1e6)
constexpr int NB = 16;
constexpr int NQ = 2048;
constexpr int NK = 2048;
constexpr int ND = 128;
constexpr int KVBLK = 64;                 // prep tile (kv)
constexpr int NTILE = NK / KVBLK;         // 32
constexpr int TILE_USH = KVBLK * ND;      // 8192 ushorts = 16KB per tile
// 1/sqrt(128) * log2(e): QK^T emits log2-domain scores; exp -> v_exp_f32 (2^x)
constexpr float SCALE2 = 0.12751744751442557f;

typedef __attribute__((ext_vector_type(4))) float f4;
typedef __attribute__((ext_vector_type(16))) float f32x16;
typedef __attribute__((ext_vector_type(8))) unsigned short us8;
typedef __attribute__((ext_vector_type(8))) __bf16 bf16x8;
typedef __attribute__((ext_vector_type(4))) unsigned int u32x4;

static __device__ __forceinline__ unsigned short f2bf(float f) {
    unsigned u = __builtin_bit_cast(unsigned, f);
    u += 0x7fffu + ((u >> 16) & 1u);
    return (unsigned short)(u >> 16);
}
static __device__ __forceinline__ f4 splat4(float x) { f4 r = {x,x,x,x}; return r; }

static __device__ __forceinline__ float fexp2(float x) {
    float r;
    asm("v_exp_f32 %0, %1" : "=v"(r) : "v"(x));
    return r;
}

static __device__ __forceinline__ void load_lds16(const unsigned short* g, unsigned short* l) {
    __builtin_amdgcn_global_load_lds(
        (const __attribute__((address_space(1))) void*)g,
        (__attribute__((address_space(3))) void*)l,
        16, 0, 0);
}

static __device__ __forceinline__ unsigned cvt_pk_bf16(float lo, float hi) {
    unsigned r;
    asm("v_cvt_pk_bf16_f32 %0, %1, %2" : "=v"(r) : "v"(lo), "v"(hi));
    return r;
}

// ---------------------------------------------------------------------------
// Prep: per (batch, kv-tile=64) write K and V in lane-linear 32x32-MFMA
// fragment order (verified R5-R15):
//  K  (kv,d): off = ((kv>>5)*8 + (d>>4))*512 + ((d>>3)&1)*256 + (kv&31)*8 + (d&7)
//  V  (kv,d): off = ((kv>>4)*4 + (d>>5))*512 + ((kv>>3)&1)*256 + (d&31)*8 + (kv&7)
// Note: each 32-kv HALF of a tile is a contiguous 8KB sub-region in both K
// and V layouts (bits 0-4 of kv unchanged; frag base shifts by 8/4 frags) —
// the attention kernel consumes 32-kv subtiles directly.
// Early-exit for tiles beyond valid length. grid (NTILE, NB), 256 threads
// ---------------------------------------------------------------------------
__global__ __launch_bounds__(256)
void prep_kv5(const float* __restrict__ kg, const float* __restrict__ vg,
              const int* __restrict__ vlen,
              unsigned short* __restrict__ wk, unsigned short* __restrict__ wvt)
{
    const int b   = blockIdx.y;
    const int t   = blockIdx.x;
    const int kv0 = t * KVBLK;

    {
        const int v = vlen[b];
        const int Leff = (v <= 0) ? NK : v;
        if (kv0 >= Leff) return;
    }

    const int t0  = threadIdx.x;

    __shared__ __align__(16) unsigned short vl[64 * 136];

    {
        const int kv = t0 >> 2;
        const int c  = t0 & 3;
        const float* gp = kg + (size_t)(b * NK + kv0 + kv) * ND + c * 32;
        unsigned short* ob = wk + (size_t)(b * NTILE + t) * TILE_USH;
        #pragma unroll
        for (int g = 0; g < 4; ++g) {
            f4 f0 = *(const f4*)(gp + g * 8);
            f4 f1 = *(const f4*)(gp + g * 8 + 4);
            us8 w;
            #pragma unroll
            for (int i = 0; i < 4; ++i) { w[i] = f2bf(f0[i]); w[i+4] = f2bf(f1[i]); }
            const int d0 = c * 32 + g * 8;
            const int f  = (kv >> 5) * 8 + (d0 >> 4);
            const int off = f * 512 + ((d0 >> 3) & 1) * 256 + (kv & 31) * 8;
            *(us8*)(ob + off) = w;
        }
    }
    {
        const int kv = t0 >> 2;
        const int d0 = (t0 & 3) * 32;
        const float* gp = vg + (size_t)(b * NK + kv0 + kv) * ND + d0;
        unsigned short* lb = &vl[kv * 136 + d0];
        #pragma unroll
        for (int g = 0; g < 4; ++g) {
            f4 f0 = *(const f4*)(gp + g * 8);
            f4 f1 = *(const f4*)(gp + g * 8 + 4);
            us8 w;
            #pragma unroll
            for (int i = 0; i < 4; ++i) { w[i] = f2bf(f0[i]); w[i+4] = f2bf(f1[i]); }
            *(us8*)(lb + g * 8) = w;
        }
    }
    __syncthreads();
    {
        unsigned short* ob = wvt + (size_t)(b * NTILE + t) * TILE_USH;
        #pragma unroll
        for (int iter = 0; iter < 4; ++iter) {
            const int cid = iter * 256 + t0;
            const int f   = cid >> 6;
            const int l   = cid & 63;
            const int kb  = (f >> 2) * 16 + (l >> 5) * 8;
            const int d   = (f & 3) * 32 + (l & 31);
            us8 w;
            #pragma unroll
            for (int j = 0; j < 8; ++j) w[j] = vl[(kb + j) * 136 + d];
            *(us8*)(ob + cid * 8) = w;
        }
    }
}

// ---------------------------------------------------------------------------
// Fused attention v16: R14 frame (256-thr blocks, 2 KV-groups x 2 q-waves,
// complementary-rank batch pairing, log2 softmax) but DOUBLE-BUFFERED 32-kv
// subtiles: one barrier per iteration; DMA issued at iteration top (covered
// by the full body); halved per-iteration register arrays.
// LDS: [group][buf][K 8KB | V 8KB] = 64KB -> 2 blocks/CU.
// ---------------------------------------------------------------------------
__global__ __launch_bounds__(256, 2)
void attn_fused16(const float* __restrict__ qg, const int* __restrict__ vlen,
                  const unsigned short* __restrict__ wk,
                  const unsigned short* __restrict__ wvt,
                  float* __restrict__ og)
{
    const int bid  = blockIdx.x;
    const int half = bid >> 8;      // 0: long ranks 0-7, 1: short ranks 15-8
    const int j    = bid & 255;
    const int rank = half ? (15 - (j & 7)) : (j & 7);
    const int qc   = j >> 3;        // 0..31
    const int q0   = qc * 64;

    // batch with this Leff-descending rank (ties by index)
    int b = 0;
    {
        int Ls[16];
        #pragma unroll
        for (int i = 0; i < 16; ++i) {
            const int v = vlen[i];
            Ls[i] = (v <= 0) ? NK : v;
        }
        #pragma unroll
        for (int bb = 0; bb < 16; ++bb) {
            int r = 0;
            #pragma unroll
            for (int cc = 0; cc < 16; ++cc)
                r += (Ls[cc] > Ls[bb] || (Ls[cc] == Ls[bb] && cc < bb)) ? 1 : 0;
            if (r == rank) b = bb;
        }
    }

    const int tid  = threadIdx.x;
    const int wid  = tid >> 6;
    const int grp  = wid >> 1;     // KV-split group 0/1 (subtiles s%2==grp)
    const int qw   = wid & 1;      // q-chunk within block (32 rows each)
    const int lane = tid & 63;
    const int lq   = lane & 31;
    const int hi   = lane >> 5;

    const int L = vlen[b];
    const bool uniform = (L <= 0);
    const int Leff = uniform ? NK : L;
    const int nsub = (Leff + 31) >> 5;          // 32-kv subtiles
    const int ng    = (nsub > grp) ? ((nsub - grp + 1) >> 1) : 0;
    const int niter = (nsub + 1) >> 1;

    // [group][buf][K 4096 ush | V 4096 ush] = 64 KB total
    __shared__ __align__(16) unsigned short smem[2][2][8192];

    // ---- Q fragments (B-operand), scaled by 1/sqrt(D)*log2(e)
    bf16x8 aq[8];
    {
        const float* qp = qg + (size_t)(b * NQ + q0 + qw * 32 + lq) * ND + hi * 8;
        #pragma unroll
        for (int c = 0; c < 8; ++c) {
            f4 f0 = *(const f4*)(qp + c * 16);
            f4 f1 = *(const f4*)(qp + c * 16 + 4);
            us8 u;
            #pragma unroll
            for (int i = 0; i < 4; ++i) {
                u[i]     = f2bf(f0[i] * SCALE2);
                u[i + 4] = f2bf(f1[i] * SCALE2);
            }
            aq[c] = __builtin_bit_cast(bf16x8, u);
        }
    }

    const unsigned short* kbg = wk  + (size_t)b * NTILE * TILE_USH;
    const unsigned short* vbg = wvt + (size_t)b * NTILE * TILE_USH;

    // staging: wave qw=0 stages K subtile (8KB), qw=1 stages V subtile (8KB)
    const unsigned short* sbase = qw ? vbg : kbg;
    const int s_off = lane * 8;

    float m_r = -__builtin_inff();
    float l_r = 0.f;
    f32x16 accO[4];
    #pragma unroll
    for (int dc = 0; dc < 4; ++dc)
        #pragma unroll
        for (int r = 0; r < 16; ++r) accO[dc][r] = 0.f;

    // subtile s -> global offset: tile (s>>1)*TILE_USH + (s&1)*4096 ushorts
    // ---- prologue: stage subtile grp into buf 0
    if (grp < nsub) {
        const int s = grp;
        const unsigned short* src =
            sbase + (size_t)(s >> 1) * TILE_USH + (s & 1) * 4096 + s_off;
        unsigned short* dst = &smem[grp][0][qw * 4096];
        #pragma unroll
        for (int jj = 0; jj < 8; ++jj) load_lds16(src + jj * 512, dst + jj * 512);
    }
    __syncthreads();

    for (int i = 0; i < niter; ++i) {
        const int buf = i & 1;

        // ---- issue next subtile's DMA into the other buffer (top of body:
        // covered by the full QK+SM+PV below; other buffer's readers finished
        // last iteration, fenced by the previous barrier)
        {
            const int sn = 2 * (i + 1) + grp;
            if (sn < nsub) {
                const unsigned short* src =
                    sbase + (size_t)(sn >> 1) * TILE_USH + (sn & 1) * 4096 + s_off;
                unsigned short* dst = &smem[grp][buf ^ 1][qw * 4096];
                #pragma unroll
                for (int jj = 0; jj < 8; ++jj) load_lds16(src + jj * 512, dst + jj * 512);
            }
        }

        if (i < ng) {
            const int s   = 2 * i + grp;
            const int kv0 = s * 32;
            const unsigned short* kl  = &smem[grp][buf][0];
            const unsigned short* vl2 = &smem[grp][buf][4096];

            // ---- K frags -> regs, QK^T (swapped: S^T[32k x 32q], log2 dom)
            us8 kf[8];
            #pragma unroll
            for (int c = 0; c < 8; ++c)
                kf[c] = *(const us8*)&kl[c * 512 + lane * 8];
            f32x16 sA;
            #pragma unroll
            for (int r = 0; r < 16; ++r) sA[r] = 0.f;
            #pragma unroll
            for (int c = 0; c < 8; ++c)
                sA = __builtin_amdgcn_mfma_f32_32x32x16_bf16(
                    __builtin_bit_cast(bf16x8, kf[c]), aq[c], sA, 0, 0, 0);
            __builtin_amdgcn_sched_barrier(0);   // VGPR peak control
            // ---- V frags -> regs
            us8 vf[8];
            #pragma unroll
            for (int f = 0; f < 8; ++f)
                vf[f] = *(const us8*)&vl2[f * 512 + lane * 8];

            // ---- mask (rows = k)
            if (uniform) {
                #pragma unroll
                for (int r = 0; r < 16; ++r) sA[r] = 0.f;
            } else {
                const int lim0 = L - kv0 - 4 * hi;
                #pragma unroll
                for (int r = 0; r < 16; ++r) {
                    const int rc = (r & 3) + 8 * (r >> 2);
                    sA[r] = (rc >= lim0) ? -__builtin_inff() : sA[r];
                }
            }

            // ---- in-register softmax for q = lq (log2 domain)
            float mx[8];
            #pragma unroll
            for (int i2 = 0; i2 < 8; ++i2)
                mx[i2] = fmaxf(sA[i2], sA[i2 + 8]);
            #pragma unroll
            for (int i2 = 0; i2 < 4; ++i2) mx[i2] = fmaxf(mx[i2], mx[i2 + 4]);
            float pm = fmaxf(fmaxf(mx[0], mx[1]), fmaxf(mx[2], mx[3]));
            float pmax = fmaxf(pm, __shfl_xor(pm, 32));

            // T13: rescale only when some q-row got a new max
            if (__any(pmax > m_r)) {
                const float mnew = fmaxf(m_r, pmax);
                const float sc = fexp2(m_r - mnew);
                m_r = mnew;
                l_r *= sc;
                #pragma unroll
                for (int r = 0; r < 16; ++r) {
                    const int src = ((r & 3) + 8 * (r >> 2) + 4 * hi) + (lane & 32);
                    const float scr = __shfl(sc, src);
                    accO[0][r] *= scr; accO[1][r] *= scr;
                    accO[2][r] *= scr; accO[3][r] *= scr;
                }
            }

            // ---- 2^x + row-sum
            float p0[16];
            #pragma unroll
            for (int r = 0; r < 16; ++r) p0[r] = fexp2(sA[r] - m_r);
            float sm[8];
            #pragma unroll
            for (int i2 = 0; i2 < 8; ++i2) sm[i2] = p0[i2] + p0[i2 + 8];
            #pragma unroll
            for (int i2 = 0; i2 < 4; ++i2) sm[i2] += sm[i2 + 4];
            float rsum = (sm[0] + sm[1]) + (sm[2] + sm[3]);
            rsum += __shfl_xor(rsum, 32);
            l_r += rsum;

            // ---- P -> bf16 packed words; half-exchange builds PV A-frags
            unsigned cw[8];
            #pragma unroll
            for (int i2 = 0; i2 < 8; ++i2) cw[i2] = cvt_pk_bf16(p0[2 * i2], p0[2 * i2 + 1]);

            bf16x8 pa[2];
            #pragma unroll
            for (int ks = 0; ks < 2; ++ks) {
                const int a = 4 * ks;
                const unsigned u = hi ? cw[a]     : cw[a + 2];
                const unsigned v = hi ? cw[a + 1] : cw[a + 3];
                const unsigned up = __shfl_xor((int)u, 32);
                const unsigned vp = __shfl_xor((int)v, 32);
                u32x4 w;
                w[0] = hi ? up        : cw[a];
                w[1] = hi ? vp        : cw[a + 1];
                w[2] = hi ? cw[a + 2] : up;
                w[3] = hi ? cw[a + 3] : vp;
                pa[ks] = __builtin_bit_cast(bf16x8, w);
            }

            // ---- PV from regs: O[32q x 128d] += P(32x32) . V(32x128)
            #pragma unroll
            for (int dc = 0; dc < 4; ++dc) {
                #pragma unroll
                for (int ks = 0; ks < 2; ++ks) {
                    accO[dc] = __builtin_amdgcn_mfma_f32_32x32x16_bf16(
                        pa[ks], __builtin_bit_cast(bf16x8, vf[ks * 4 + dc]), accO[dc], 0, 0, 0);
                }
            }
        }

        // single barrier: drains this iteration's DMA (vmcnt 0, covered by
        // the body above) and fences buffer rotation
        __syncthreads();
    }

    // ---- merge epilogue: group1 -> LDS (32KB accO + m/l), group0 combines
    float* accb = (float*)&smem[0][0][0];
    float* mlb  = accb + 8192;            // 128 floats
    if (grp == 1) {
        #pragma unroll
        for (int dc = 0; dc < 4; ++dc) {
            #pragma unroll
            for (int q4 = 0; q4 < 4; ++q4) {
                f4 v;
                #pragma unroll
                for (int c = 0; c < 4; ++c) v[c] = accO[dc][q4 * 4 + c];
                *(f4*)&accb[(((qw * 16 + dc * 4 + q4) * 64) + lane) * 4] = v;
            }
        }
        if (hi == 0) {
            mlb[qw * 32 + lq]      = m_r;
            mlb[64 + qw * 32 + lq] = l_r;
        }
    }
    __syncthreads();
    if (grp == 0) {
        const float m1 = mlb[qw * 32 + lq];
        const float l1 = mlb[64 + qw * 32 + lq];
        const float m  = fmaxf(m_r, m1);
        const float a0 = fexp2(m_r - m), a1 = fexp2(m1 - m);
        const float linv = 1.0f / (a0 * l_r + a1 * l1);
        const float s0v = a0 * linv, s1v = a1 * linv;
        float* ob = og + (size_t)(b * NQ + q0 + qw * 32) * ND;
        #pragma unroll
        for (int dc = 0; dc < 4; ++dc) {
            #pragma unroll
            for (int q4 = 0; q4 < 4; ++q4) {
                f4 o1 = *(const f4*)&accb[(((qw * 16 + dc * 4 + q4) * 64) + lane) * 4];
                #pragma unroll
                for (int c = 0; c < 4; ++c) {
                    const int r = q4 * 4 + c;
                    const int row = c + 8 * q4 + 4 * hi;
                    const float s0r = __shfl(s0v, row + (lane & 32));
                    const float s1r = __shfl(s1v, row + (lane & 32));
                    ob[(size_t)row * ND + dc * 32 + lq] = accO[dc][r] * s0r + o1[c] * s1r;
                }
            }
        }
    }
}

// ---------------------------------------------------------------------------
// Fallback (R1 kernel): used only if ws_size < 16 MB
// ---------------------------------------------------------------------------
__global__ __launch_bounds__(256, 2)
void attn_fused(const float* __restrict__ qg, const float* __restrict__ kg,
                const float* __restrict__ vg, const int* __restrict__ vlen,
                float* __restrict__ og)
{
    const int b    = blockIdx.y;
    const int q0   = blockIdx.x * 64;
    const int tid  = threadIdx.x;
    const int wid  = tid >> 6;
    const int lane = tid & 63;
    const int lrow = lane & 15;
    const int lgrp = lane >> 4;
    constexpr float SCALE = 0.08838834764831844f;

    const int L = vlen[b];
    const bool uniform = (L <= 0);
    const int Leff = uniform ? NK : L;
    const int nt32 = (Leff + 31) / 32;

    __shared__ __align__(16) unsigned short kt[32 * 136];
    __shared__ __align__(16) unsigned short vt[128 * 40];
    __shared__ __align__(16) float pt[4][16 * 36];

    bf16x8 aqf[4];
    {
        const float* qp = qg + (size_t)(b * NQ + q0 + wid * 16 + lrow) * ND + lgrp * 8;
        #pragma unroll
        for (int c = 0; c < 4; ++c) {
            f4 f0 = *(const f4*)(qp + c * 32);
            f4 f1 = *(const f4*)(qp + c * 32 + 4);
            us8 u;
            #pragma unroll
            for (int i = 0; i < 4; ++i) {
                u[i]     = f2bf(f0[i] * SCALE);
                u[i + 4] = f2bf(f1[i] * SCALE);
            }
            aqf[c] = __builtin_bit_cast(bf16x8, u);
        }
    }

    float m_r[4], l_r[4];
    f4 accO[8];
    #pragma unroll
    for (int r = 0; r < 4; ++r) { m_r[r] = -__builtin_inff(); l_r[r] = 0.f; }
    #pragma unroll
    for (int dc = 0; dc < 8; ++dc) accO[dc] = splat4(0.f);

    for (int t = 0; t < nt32; ++t) {
        const int kv0 = t * 32;
        __syncthreads();
        {
            const int r  = tid >> 3;
            const int c0 = (tid & 7) * 16;
            const float* gp = kg + (size_t)(b * NK + kv0 + r) * ND + c0;
            f4 f0 = *(const f4*)(gp);
            f4 f1 = *(const f4*)(gp + 4);
            f4 f2 = *(const f4*)(gp + 8);
            f4 f3 = *(const f4*)(gp + 12);
            us8 w0, w1;
            #pragma unroll
            for (int i = 0; i < 4; ++i) {
                w0[i]     = f2bf(f0[i]);
                w0[i + 4] = f2bf(f1[i]);
                w1[i]     = f2bf(f2[i]);
                w1[i + 4] = f2bf(f3[i]);
            }
            unsigned short* dst = &kt[r * 136 + c0];
            *(us8*)(dst)     = w0;
            *(us8*)(dst + 8) = w1;
        }
        {
            const int d  = tid & 127;
            const int g2 = tid >> 7;
            const float* gp = vg + (size_t)(b * NK + kv0 + g2 * 16) * ND + d;
            us8 w0, w1;
            #pragma unroll
            for (int jj = 0; jj < 8; ++jj) {
                w0[jj] = f2bf(gp[(size_t)jj * ND]);
                w1[jj] = f2bf(gp[(size_t)(jj + 8) * ND]);
            }
            unsigned short* dst = &vt[d * 40 + g2 * 16];
            *(us8*)(dst)     = w0;
            *(us8*)(dst + 8) = w1;
        }
        __syncthreads();

        f4 s0 = splat4(0.f), s1 = splat4(0.f);
        #pragma unroll
        for (int c = 0; c < 4; ++c) {
            bf16x8 bk0 = __builtin_bit_cast(bf16x8,
                *(const us8*)&kt[lrow * 136 + c * 32 + lgrp * 8]);
            s0 = __builtin_amdgcn_mfma_f32_16x16x32_bf16(aqf[c], bk0, s0, 0, 0, 0);
            bf16x8 bk1 = __builtin_bit_cast(bf16x8,
                *(const us8*)&kt[(16 + lrow) * 136 + c * 32 + lgrp * 8]);
            s1 = __builtin_amdgcn_mfma_f32_16x16x32_bf16(aqf[c], bk1, s1, 0, 0, 0);
        }

        const int col0 = kv0 + lrow;
        if (uniform) {
            s0 = splat4(0.f);
            s1 = splat4(0.f);
        } else {
            if (col0 >= L)      s0 = splat4(-__builtin_inff());
            if (col0 + 16 >= L) s1 = splat4(-__builtin_inff());
        }

        float pm[4];
        #pragma unroll
        for (int r = 0; r < 4; ++r) pm[r] = fmaxf(s0[r], s1[r]);
        #pragma unroll
        for (int off = 8; off > 0; off >>= 1) {
            #pragma unroll
            for (int r = 0; r < 4; ++r)
                pm[r] = fmaxf(pm[r], __shfl_xor(pm[r], off));
        }
        float pr0[4], pr1[4], rs[4], sc[4];
        #pragma unroll
        for (int r = 0; r < 4; ++r) {
            float mn = fmaxf(m_r[r], pm[r]);
            sc[r]  = __expf(m_r[r] - mn);
            m_r[r] = mn;
            pr0[r] = __expf(s0[r] - mn);
            pr1[r] = __expf(s1[r] - mn);
            rs[r]  = pr0[r] + pr1[r];
        }
        #pragma unroll
        for (int off = 8; off > 0; off >>= 1) {
            #pragma unroll
            for (int r = 0; r < 4; ++r)
                rs[r] += __shfl_xor(rs[r], off);
        }
        #pragma unroll
        for (int r = 0; r < 4; ++r) l_r[r] = l_r[r] * sc[r] + rs[r];
        #pragma unroll
        for (int dc = 0; dc < 8; ++dc) {
            #pragma unroll
            for (int r = 0; r < 4; ++r) accO[dc][r] *= sc[r];
        }

        float* pw = pt[wid];
        #pragma unroll
        for (int r = 0; r < 4; ++r) {
            pw[(lgrp * 4 + r) * 36 + lrow]      = pr0[r];
            pw[(lgrp * 4 + r) * 36 + 16 + lrow] = pr1[r];
        }
        asm volatile("s_waitcnt lgkmcnt(0)" ::: "memory");
        f4 a0 = *(const f4*)&pw[lrow * 36 + lgrp * 8];
        f4 a1 = *(const f4*)&pw[lrow * 36 + lgrp * 8 + 4];
        us8 au;
        #pragma unroll
        for (int i = 0; i < 4; ++i) { au[i] = f2bf(a0[i]); au[i + 4] = f2bf(a1[i]); }
        bf16x8 ap = __builtin_bit_cast(bf16x8, au);

        #pragma unroll
        for (int dc = 0; dc < 8; ++dc) {
            bf16x8 bv = __builtin_bit_cast(bf16x8,
                *(const us8*)&vt[(dc * 16 + lrow) * 40 + lgrp * 8]);
            accO[dc] = __builtin_amdgcn_mfma_f32_16x16x32_bf16(ap, bv, accO[dc], 0, 0, 0);
        }
    }

    float inv[4];
    #pragma unroll
    for (int r = 0; r < 4; ++r) inv[r] = 1.0f / l_r[r];
    float* op = og + (size_t)(b * NQ + q0 + wid * 16) * ND;
    #pragma unroll
    for (int dc = 0; dc < 8; ++dc) {
        #pragma unroll
        for (int r = 0; r < 4; ++r)
            op[(lgrp * 4 + r) * ND + dc * 16 + lrow] = accO[dc][r] * inv[r];
    }
}

extern "C" void kernel_launch(void* const* d_in, const int* in_sizes, int n_in,
                              void* d_out, int out_size, void* d_ws, size_t ws_size,
                              hipStream_t stream) {
    (void)in_sizes; (void)n_in; (void)out_size;
    const float* q  = (const float*)d_in[0];
    const float* k  = (const float*)d_in[1];
    const float* v  = (const float*)d_in[2];
    const int*   vl = (const int*)d_in[3];
    float* out = (float*)d_out;

    const size_t kvbytes = 2 * (size_t)NB * NK * ND * sizeof(unsigned short); // 16 MB
    if (ws_size >= kvbytes) {
        unsigned short* wk  = (unsigned short*)d_ws;
        unsigned short* wvt = wk + (size_t)NB * NK * ND;
        hipLaunchKernelGGL(prep_kv5, dim3(NTILE, NB), dim3(256), 0, stream, k, v, vl, wk, wvt);
        hipLaunchKernelGGL(attn_fused16, dim3((NQ / 64) * NB), dim3(256), 0, stream,
                           q, vl, wk, wvt, out);
    } else {
        hipLaunchKernelGGL(attn_fused, dim3(NQ / 64, NB), dim3(256), 0, stream,
                           q, k, v, vl, out);
    }
}

// Round 17
// 56.789 us; speedup vs baseline: 1.0536x; 1.0536x over previous
//
#include <hip/hip_runtime.h>

// Problem constants (reference: B=16, Q=2048, K=2048, D=128, fp32, NEG=-1e6)
constexpr int NB = 16;
constexpr int NQ = 2048;
constexpr int NK = 2048;
constexpr int ND = 128;
constexpr int KVBLK = 64;                 // kv per tile
constexpr int NTILE = NK / KVBLK;         // 32
constexpr int TILE_USH = KVBLK * ND;      // 8192 ushorts = 16KB per tile
// 1/sqrt(128) * log2(e): QK^T emits log2-domain scores; exp -> v_exp_f32 (2^x)
constexpr float SCALE2 = 0.12751744751442557f;

typedef __attribute__((ext_vector_type(4))) float f4;
typedef __attribute__((ext_vector_type(16))) float f32x16;
typedef __attribute__((ext_vector_type(8))) unsigned short us8;
typedef __attribute__((ext_vector_type(8))) __bf16 bf16x8;
typedef __attribute__((ext_vector_type(4))) unsigned int u32x4;

static __device__ __forceinline__ unsigned short f2bf(float f) {
    unsigned u = __builtin_bit_cast(unsigned, f);
    u += 0x7fffu + ((u >> 16) & 1u);
    return (unsigned short)(u >> 16);
}
static __device__ __forceinline__ f4 splat4(float x) { f4 r = {x,x,x,x}; return r; }

static __device__ __forceinline__ float fexp2(float x) {
    float r;
    asm("v_exp_f32 %0, %1" : "=v"(r) : "v"(x));
    return r;
}

static __device__ __forceinline__ void load_lds16(const unsigned short* g, unsigned short* l) {
    __builtin_amdgcn_global_load_lds(
        (const __attribute__((address_space(1))) void*)g,
        (__attribute__((address_space(3))) void*)l,
        16, 0, 0);
}

static __device__ __forceinline__ unsigned cvt_pk_bf16(float lo, float hi) {
    unsigned r;
    asm("v_cvt_pk_bf16_f32 %0, %1, %2" : "=v"(r) : "v"(lo), "v"(hi));
    return r;
}

// ---------------------------------------------------------------------------
// Prep: per (batch, kv-tile=64) write K and V in lane-linear 32x32-MFMA
// fragment order (verified R5-R16):
//  K  (kv,d): off = ((kv>>5)*8 + (d>>4))*512 + ((d>>3)&1)*256 + (kv&31)*8 + (d&7)
//  V  (kv,d): off = ((kv>>4)*4 + (d>>5))*512 + ((kv>>3)&1)*256 + (d&31)*8 + (kv&7)
// Early-exit for tiles beyond valid length (attn never reads them).
// grid (NTILE, NB), 256 threads
// ---------------------------------------------------------------------------
__global__ __launch_bounds__(256)
void prep_kv5(const float* __restrict__ kg, const float* __restrict__ vg,
              const int* __restrict__ vlen,
              unsigned short* __restrict__ wk, unsigned short* __restrict__ wvt)
{
    const int b   = blockIdx.y;
    const int t   = blockIdx.x;
    const int kv0 = t * KVBLK;

    {
        const int v = vlen[b];
        const int Leff = (v <= 0) ? NK : v;
        if (kv0 >= Leff) return;
    }

    const int t0  = threadIdx.x;

    __shared__ __align__(16) unsigned short vl[64 * 136];

    {
        const int kv = t0 >> 2;
        const int c  = t0 & 3;
        const float* gp = kg + (size_t)(b * NK + kv0 + kv) * ND + c * 32;
        unsigned short* ob = wk + (size_t)(b * NTILE + t) * TILE_USH;
        #pragma unroll
        for (int g = 0; g < 4; ++g) {
            f4 f0 = *(const f4*)(gp + g * 8);
            f4 f1 = *(const f4*)(gp + g * 8 + 4);
            us8 w;
            #pragma unroll
            for (int i = 0; i < 4; ++i) { w[i] = f2bf(f0[i]); w[i+4] = f2bf(f1[i]); }
            const int d0 = c * 32 + g * 8;
            const int f  = (kv >> 5) * 8 + (d0 >> 4);
            const int off = f * 512 + ((d0 >> 3) & 1) * 256 + (kv & 31) * 8;
            *(us8*)(ob + off) = w;
        }
    }
    {
        const int kv = t0 >> 2;
        const int d0 = (t0 & 3) * 32;
        const float* gp = vg + (size_t)(b * NK + kv0 + kv) * ND + d0;
        unsigned short* lb = &vl[kv * 136 + d0];
        #pragma unroll
        for (int g = 0; g < 4; ++g) {
            f4 f0 = *(const f4*)(gp + g * 8);
            f4 f1 = *(const f4*)(gp + g * 8 + 4);
            us8 w;
            #pragma unroll
            for (int i = 0; i < 4; ++i) { w[i] = f2bf(f0[i]); w[i+4] = f2bf(f1[i]); }
            *(us8*)(lb + g * 8) = w;
        }
    }
    __syncthreads();
    {
        unsigned short* ob = wvt + (size_t)(b * NTILE + t) * TILE_USH;
        #pragma unroll
        for (int iter = 0; iter < 4; ++iter) {
            const int cid = iter * 256 + t0;
            const int f   = cid >> 6;
            const int l   = cid & 63;
            const int kb  = (f >> 2) * 16 + (l >> 5) * 8;
            const int d   = (f & 3) * 32 + (l & 31);
            us8 w;
            #pragma unroll
            for (int j = 0; j < 8; ++j) w[j] = vl[(kb + j) * 136 + d];
            *(us8*)(ob + cid * 8) = w;
        }
    }
}

// ---------------------------------------------------------------------------
// Fused attention v17 = R14 (measured best 56.9us): 256-thr blocks, QBLK=64,
// 2 KV-groups x 2 q-waves, 64KB LDS single-buffer DMA rotation,
// complementary-rank batch pairing, log2-domain softmax.
// R17 delta: 3-ary max reduce (v_max3 fusion) on the serial softmax path.
// ---------------------------------------------------------------------------
__global__ __launch_bounds__(256, 2)
void attn_fused17(const float* __restrict__ qg, const int* __restrict__ vlen,
                  const unsigned short* __restrict__ wk,
                  const unsigned short* __restrict__ wvt,
                  float* __restrict__ og)
{
    const int bid  = blockIdx.x;
    const int half = bid >> 8;      // 0: long ranks 0-7, 1: short ranks 15-8
    const int j    = bid & 255;
    const int rank = half ? (15 - (j & 7)) : (j & 7);
    const int qc   = j >> 3;        // 0..31
    const int q0   = qc * 64;

    // batch with this Leff-descending rank (ties by index)
    int b = 0;
    {
        int Ls[16];
        #pragma unroll
        for (int i = 0; i < 16; ++i) {
            const int v = vlen[i];
            Ls[i] = (v <= 0) ? NK : v;
        }
        #pragma unroll
        for (int bb = 0; bb < 16; ++bb) {
            int r = 0;
            #pragma unroll
            for (int cc = 0; cc < 16; ++cc)
                r += (Ls[cc] > Ls[bb] || (Ls[cc] == Ls[bb] && cc < bb)) ? 1 : 0;
            if (r == rank) b = bb;
        }
    }

    const int tid  = threadIdx.x;
    const int wid  = tid >> 6;
    const int grp  = wid >> 1;     // KV-split group 0/1
    const int qw   = wid & 1;      // q-chunk within block (32 rows each)
    const int lane = tid & 63;
    const int lq   = lane & 31;
    const int hi   = lane >> 5;

    const int L = vlen[b];
    const bool uniform = (L <= 0);
    const int Leff = uniform ? NK : L;
    const int ntiles = (Leff + KVBLK - 1) / KVBLK;
    const int ng    = (ntiles + 1 - grp) >> 1;
    const int niter = (ntiles + 1) >> 1;

    // [group][K 16KB | V 16KB] single-buffered = 64 KB total
    __shared__ __align__(16) unsigned short smem[2][2 * TILE_USH];

    // ---- Q fragments (B-operand), scaled by 1/sqrt(D)*log2(e)
    bf16x8 aq[8];
    {
        const float* qp = qg + (size_t)(b * NQ + q0 + qw * 32 + lq) * ND + hi * 8;
        #pragma unroll
        for (int c = 0; c < 8; ++c) {
            f4 f0 = *(const f4*)(qp + c * 16);
            f4 f1 = *(const f4*)(qp + c * 16 + 4);
            us8 u;
            #pragma unroll
            for (int i = 0; i < 4; ++i) {
                u[i]     = f2bf(f0[i] * SCALE2);
                u[i + 4] = f2bf(f1[i] * SCALE2);
            }
            aq[c] = __builtin_bit_cast(bf16x8, u);
        }
    }

    const unsigned short* kbg = wk  + (size_t)b * NTILE * TILE_USH;
    const unsigned short* vbg = wvt + (size_t)b * NTILE * TILE_USH;

    // staging: wave qw=0 stages K (16KB), qw=1 stages V (16KB), 16 x 1KB DMA
    const unsigned short* sbase = qw ? vbg : kbg;
    unsigned short* sdst = &smem[grp][qw * 8192];
    const int s_off = lane * 8;

    float m_r = -__builtin_inff();
    float l_r = 0.f;
    f32x16 accO[4];
    #pragma unroll
    for (int dc = 0; dc < 4; ++dc)
        #pragma unroll
        for (int r = 0; r < 16; ++r) accO[dc][r] = 0.f;

    // ---- prologue: stage tile grp
    if (grp < ntiles) {
        const unsigned short* src = sbase + (size_t)grp * TILE_USH + s_off;
        #pragma unroll
        for (int jj = 0; jj < 16; ++jj) load_lds16(src + jj * 512, sdst + jj * 512);
    }
    __syncthreads();

    for (int i = 0; i < niter; ++i) {
        const int tile = 2 * i + grp;
        const unsigned short* kl  = &smem[grp][0];
        const unsigned short* vl2 = &smem[grp][8192];
        const bool act = (i < ng);

        us8 kf[16], vf[16];
        f32x16 sA, sB;
        if (act) {
            // ---- K frags -> regs, QK^T (swapped: S^T[64k x 32q], log2 domain)
            #pragma unroll
            for (int c = 0; c < 16; ++c)
                kf[c] = *(const us8*)&kl[c * 512 + lane * 8];
            #pragma unroll
            for (int r = 0; r < 16; ++r) { sA[r] = 0.f; sB[r] = 0.f; }
            #pragma unroll
            for (int c = 0; c < 8; ++c) {
                sA = __builtin_amdgcn_mfma_f32_32x32x16_bf16(
                    __builtin_bit_cast(bf16x8, kf[c]), aq[c], sA, 0, 0, 0);
                sB = __builtin_amdgcn_mfma_f32_32x32x16_bf16(
                    __builtin_bit_cast(bf16x8, kf[8 + c]), aq[c], sB, 0, 0, 0);
            }
            __builtin_amdgcn_sched_barrier(0);   // VGPR peak control
            // ---- V frags -> regs
            #pragma unroll
            for (int f = 0; f < 16; ++f)
                vf[f] = *(const us8*)&vl2[f * 512 + lane * 8];
        }

        // BARRIER A: all ds_reads drained (implicit lgkmcnt(0)) -> buffer free
        __syncthreads();

        // ---- issue next tile's DMA into the (now free) buffer
        {
            const int tn = tile + 2;
            if (tn < ntiles) {
                const unsigned short* src = sbase + (size_t)tn * TILE_USH + s_off;
                #pragma unroll
                for (int jj = 0; jj < 16; ++jj) load_lds16(src + jj * 512, sdst + jj * 512);
            }
        }

        if (act) {
            const int kv0 = tile * KVBLK;

            // ---- mask (rows = k)
            if (uniform) {
                #pragma unroll
                for (int r = 0; r < 16; ++r) { sA[r] = 0.f; sB[r] = 0.f; }
            } else {
                const int lim0 = L - kv0 - 4 * hi;
                const int lim1 = lim0 - 32;
                #pragma unroll
                for (int r = 0; r < 16; ++r) {
                    const int rc = (r & 3) + 8 * (r >> 2);
                    sA[r] = (rc >= lim0) ? -__builtin_inff() : sA[r];
                    sB[r] = (rc >= lim1) ? -__builtin_inff() : sB[r];
                }
            }

            // ---- in-register softmax for q = lq (log2 domain)
            // 3-ary max tree over 32 values (clang fuses fmaxf(fmaxf(a,b),c)
            // to v_max3_f32): 32 -> 11 -> 4 -> 1
            float tt[11];
            #pragma unroll
            for (int g3 = 0; g3 < 5; ++g3)
                tt[g3] = fmaxf(fmaxf(sA[3 * g3], sA[3 * g3 + 1]), sA[3 * g3 + 2]);
            tt[5] = fmaxf(fmaxf(sA[15], sB[0]), sB[1]);
            #pragma unroll
            for (int g3 = 0; g3 < 4; ++g3)
                tt[6 + g3] = fmaxf(fmaxf(sB[3 * g3 + 2], sB[3 * g3 + 3]), sB[3 * g3 + 4]);
            tt[10] = fmaxf(sB[14], sB[15]);
            const float u0 = fmaxf(fmaxf(tt[0], tt[1]), tt[2]);
            const float u1 = fmaxf(fmaxf(tt[3], tt[4]), tt[5]);
            const float u2 = fmaxf(fmaxf(tt[6], tt[7]), tt[8]);
            const float u3 = fmaxf(tt[9], tt[10]);
            const float pm = fmaxf(fmaxf(u0, u1), fmaxf(u2, u3));
            float pmax = fmaxf(pm, __shfl_xor(pm, 32));

            // T13: rescale only when some q-row got a new max
            if (__any(pmax > m_r)) {
                const float mnew = fmaxf(m_r, pmax);
                const float sc = fexp2(m_r - mnew);
                m_r = mnew;
                l_r *= sc;
                #pragma unroll
                for (int r = 0; r < 16; ++r) {
                    const int src = ((r & 3) + 8 * (r >> 2) + 4 * hi) + (lane & 32);
                    const float scr = __shfl(sc, src);
                    accO[0][r] *= scr; accO[1][r] *= scr;
                    accO[2][r] *= scr; accO[3][r] *= scr;
                }
            }

            // ---- 2^x + row-sum
            float p0[16], p1[16];
            #pragma unroll
            for (int r = 0; r < 16; ++r) {
                p0[r] = fexp2(sA[r] - m_r);
                p1[r] = fexp2(sB[r] - m_r);
            }
            float sm[8];
            #pragma unroll
            for (int i2 = 0; i2 < 8; ++i2)
                sm[i2] = (p0[i2] + p0[i2 + 8]) + (p1[i2] + p1[i2 + 8]);
            #pragma unroll
            for (int i2 = 0; i2 < 4; ++i2) sm[i2] += sm[i2 + 4];
            float rsum = (sm[0] + sm[1]) + (sm[2] + sm[3]);
            rsum += __shfl_xor(rsum, 32);
            l_r += rsum;

            // ---- P -> bf16 packed words; half-exchange builds PV A-frags
            unsigned cw[16];
            #pragma unroll
            for (int i2 = 0; i2 < 8; ++i2) cw[i2] = cvt_pk_bf16(p0[2 * i2], p0[2 * i2 + 1]);
            #pragma unroll
            for (int i2 = 0; i2 < 8; ++i2) cw[8 + i2] = cvt_pk_bf16(p1[2 * i2], p1[2 * i2 + 1]);

            bf16x8 pa[4];
            #pragma unroll
            for (int ks = 0; ks < 4; ++ks) {
                const int a = 4 * ks;
                const unsigned u = hi ? cw[a]     : cw[a + 2];
                const unsigned v = hi ? cw[a + 1] : cw[a + 3];
                const unsigned up = __shfl_xor((int)u, 32);
                const unsigned vp = __shfl_xor((int)v, 32);
                u32x4 w;
                w[0] = hi ? up        : cw[a];
                w[1] = hi ? vp        : cw[a + 1];
                w[2] = hi ? cw[a + 2] : up;
                w[3] = hi ? cw[a + 3] : vp;
                pa[ks] = __builtin_bit_cast(bf16x8, w);
            }

            // ---- PV from regs
            #pragma unroll
            for (int dc = 0; dc < 4; ++dc) {
                #pragma unroll
                for (int ks = 0; ks < 4; ++ks) {
                    accO[dc] = __builtin_amdgcn_mfma_f32_32x32x16_bf16(
                        pa[ks], __builtin_bit_cast(bf16x8, vf[ks * 4 + dc]), accO[dc], 0, 0, 0);
                }
            }
        }

        // BARRIER B: implicit vmcnt(0) lands this iteration's DMA
        __syncthreads();
    }

    // ---- merge epilogue: group1 -> LDS (32KB accO + m/l), group0 combines
    float* accb = (float*)&smem[0][0];
    float* mlb  = accb + 8192;            // 128 floats
    if (grp == 1) {
        #pragma unroll
        for (int dc = 0; dc < 4; ++dc) {
            #pragma unroll
            for (int q4 = 0; q4 < 4; ++q4) {
                f4 v;
                #pragma unroll
                for (int c = 0; c < 4; ++c) v[c] = accO[dc][q4 * 4 + c];
                *(f4*)&accb[(((qw * 16 + dc * 4 + q4) * 64) + lane) * 4] = v;
            }
        }
        if (hi == 0) {
            mlb[qw * 32 + lq]      = m_r;
            mlb[64 + qw * 32 + lq] = l_r;
        }
    }
    __syncthreads();
    if (grp == 0) {
        const float m1 = mlb[qw * 32 + lq];
        const float l1 = mlb[64 + qw * 32 + lq];
        const float m  = fmaxf(m_r, m1);
        const float a0 = fexp2(m_r - m), a1 = fexp2(m1 - m);
        const float linv = 1.0f / (a0 * l_r + a1 * l1);
        const float s0v = a0 * linv, s1v = a1 * linv;
        float* ob = og + (size_t)(b * NQ + q0 + qw * 32) * ND;
        #pragma unroll
        for (int dc = 0; dc < 4; ++dc) {
            #pragma unroll
            for (int q4 = 0; q4 < 4; ++q4) {
                f4 o1 = *(const f4*)&accb[(((qw * 16 + dc * 4 + q4) * 64) + lane) * 4];
                #pragma unroll
                for (int c = 0; c < 4; ++c) {
                    const int r = q4 * 4 + c;
                    const int row = c + 8 * q4 + 4 * hi;
                    const float s0r = __shfl(s0v, row + (lane & 32));
                    const float s1r = __shfl(s1v, row + (lane & 32));
                    ob[(size_t)row * ND + dc * 32 + lq] = accO[dc][r] * s0r + o1[c] * s1r;
                }
            }
        }
    }
}

// ---------------------------------------------------------------------------
// Fallback (R1 kernel): used only if ws_size < 16 MB
// ---------------------------------------------------------------------------
__global__ __launch_bounds__(256, 2)
void attn_fused(const float* __restrict__ qg, const float* __restrict__ kg,
                const float* __restrict__ vg, const int* __restrict__ vlen,
                float* __restrict__ og)
{
    const int b    = blockIdx.y;
    const int q0   = blockIdx.x * 64;
    const int tid  = threadIdx.x;
    const int wid  = tid >> 6;
    const int lane = tid & 63;
    const int lrow = lane & 15;
    const int lgrp = lane >> 4;
    constexpr float SCALE = 0.08838834764831844f;

    const int L = vlen[b];
    const bool uniform = (L <= 0);
    const int Leff = uniform ? NK : L;
    const int nt32 = (Leff + 31) / 32;

    __shared__ __align__(16) unsigned short kt[32 * 136];
    __shared__ __align__(16) unsigned short vt[128 * 40];
    __shared__ __align__(16) float pt[4][16 * 36];

    bf16x8 aqf[4];
    {
        const float* qp = qg + (size_t)(b * NQ + q0 + wid * 16 + lrow) * ND + lgrp * 8;
        #pragma unroll
        for (int c = 0; c < 4; ++c) {
            f4 f0 = *(const f4*)(qp + c * 32);
            f4 f1 = *(const f4*)(qp + c * 32 + 4);
            us8 u;
            #pragma unroll
            for (int i = 0; i < 4; ++i) {
                u[i]     = f2bf(f0[i] * SCALE);
                u[i + 4] = f2bf(f1[i] * SCALE);
            }
            aqf[c] = __builtin_bit_cast(bf16x8, u);
        }
    }

    float m_r[4], l_r[4];
    f4 accO[8];
    #pragma unroll
    for (int r = 0; r < 4; ++r) { m_r[r] = -__builtin_inff(); l_r[r] = 0.f; }
    #pragma unroll
    for (int dc = 0; dc < 8; ++dc) accO[dc] = splat4(0.f);

    for (int t = 0; t < nt32; ++t) {
        const int kv0 = t * 32;
        __syncthreads();
        {
            const int r  = tid >> 3;
            const int c0 = (tid & 7) * 16;
            const float* gp = kg + (size_t)(b * NK + kv0 + r) * ND + c0;
            f4 f0 = *(const f4*)(gp);
            f4 f1 = *(const f4*)(gp + 4);
            f4 f2 = *(const f4*)(gp + 8);
            f4 f3 = *(const f4*)(gp + 12);
            us8 w0, w1;
            #pragma unroll
            for (int i = 0; i < 4; ++i) {
                w0[i]     = f2bf(f0[i]);
                w0[i + 4] = f2bf(f1[i]);
                w1[i]     = f2bf(f2[i]);
                w1[i + 4] = f2bf(f3[i]);
            }
            unsigned short* dst = &kt[r * 136 + c0];
            *(us8*)(dst)     = w0;
            *(us8*)(dst + 8) = w1;
        }
        {
            const int d  = tid & 127;
            const int g2 = tid >> 7;
            const float* gp = vg + (size_t)(b * NK + kv0 + g2 * 16) * ND + d;
            us8 w0, w1;
            #pragma unroll
            for (int jj = 0; jj < 8; ++jj) {
                w0[jj] = f2bf(gp[(size_t)jj * ND]);
                w1[jj] = f2bf(gp[(size_t)(jj + 8) * ND]);
            }
            unsigned short* dst = &vt[d * 40 + g2 * 16];
            *(us8*)(dst)     = w0;
            *(us8*)(dst + 8) = w1;
        }
        __syncthreads();

        f4 s0 = splat4(0.f), s1 = splat4(0.f);
        #pragma unroll
        for (int c = 0; c < 4; ++c) {
            bf16x8 bk0 = __builtin_bit_cast(bf16x8,
                *(const us8*)&kt[lrow * 136 + c * 32 + lgrp * 8]);
            s0 = __builtin_amdgcn_mfma_f32_16x16x32_bf16(aqf[c], bk0, s0, 0, 0, 0);
            bf16x8 bk1 = __builtin_bit_cast(bf16x8,
                *(const us8*)&kt[(16 + lrow) * 136 + c * 32 + lgrp * 8]);
            s1 = __builtin_amdgcn_mfma_f32_16x16x32_bf16(aqf[c], bk1, s1, 0, 0, 0);
        }

        const int col0 = kv0 + lrow;
        if (uniform) {
            s0 = splat4(0.f);
            s1 = splat4(0.f);
        } else {
            if (col0 >= L)      s0 = splat4(-__builtin_inff());
            if (col0 + 16 >= L) s1 = splat4(-__builtin_inff());
        }

        float pm[4];
        #pragma unroll
        for (int r = 0; r < 4; ++r) pm[r] = fmaxf(s0[r], s1[r]);
        #pragma unroll
        for (int off = 8; off > 0; off >>= 1) {
            #pragma unroll
            for (int r = 0; r < 4; ++r)
                pm[r] = fmaxf(pm[r], __shfl_xor(pm[r], off));
        }
        float pr0[4], pr1[4], rs[4], sc[4];
        #pragma unroll
        for (int r = 0; r < 4; ++r) {
            float mn = fmaxf(m_r[r], pm[r]);
            sc[r]  = __expf(m_r[r] - mn);
            m_r[r] = mn;
            pr0[r] = __expf(s0[r] - mn);
            pr1[r] = __expf(s1[r] - mn);
            rs[r]  = pr0[r] + pr1[r];
        }
        #pragma unroll
        for (int off = 8; off > 0; off >>= 1) {
            #pragma unroll
            for (int r = 0; r < 4; ++r)
                rs[r] += __shfl_xor(rs[r], off);
        }
        #pragma unroll
        for (int r = 0; r < 4; ++r) l_r[r] = l_r[r] * sc[r] + rs[r];
        #pragma unroll
        for (int dc = 0; dc < 8; ++dc) {
            #pragma unroll
            for (int r = 0; r < 4; ++r) accO[dc][r] *= sc[r];
        }

        float* pw = pt[wid];
        #pragma unroll
        for (int r = 0; r < 4; ++r) {
            pw[(lgrp * 4 + r) * 36 + lrow]      = pr0[r];
            pw[(lgrp * 4 + r) * 36 + 16 + lrow] = pr1[r];
        }
        asm volatile("s_waitcnt lgkmcnt(0)" ::: "memory");
        f4 a0 = *(const f4*)&pw[lrow * 36 + lgrp * 8];
        f4 a1 = *(const f4*)&pw[lrow * 36 + lgrp * 8 + 4];
        us8 au;
        #pragma unroll
        for (int i = 0; i < 4; ++i) { au[i] = f2bf(a0[i]); au[i + 4] = f2bf(a1[i]); }
        bf16x8 ap = __builtin_bit_cast(bf16x8, au);

        #pragma unroll
        for (int dc = 0; dc < 8; ++dc) {
            bf16x8 bv = __builtin_bit_cast(bf16x8,
                *(const us8*)&vt[(dc * 16 + lrow) * 40 + lgrp * 8]);
            accO[dc] = __builtin_amdgcn_mfma_f32_16x16x32_bf16(ap, bv, accO[dc], 0, 0, 0);
        }
    }

    float inv[4];
    #pragma unroll
    for (int r = 0; r < 4; ++r) inv[r] = 1.0f / l_r[r];
    float* op = og + (size_t)(b * NQ + q0 + wid * 16) * ND;
    #pragma unroll
    for (int dc = 0; dc < 8; ++dc) {
        #pragma unroll
        for (int r = 0; r < 4; ++r)
            op[(lgrp * 4 + r) * ND + dc * 16 + lrow] = accO[dc][r] * inv[r];
    }
}

extern "C" void kernel_launch(void* const* d_in, const int* in_sizes, int n_in,
                              void* d_out, int out_size, void* d_ws, size_t ws_size,
                              hipStream_t stream) {
    (void)in_sizes; (void)n_in; (void)out_size;
    const float* q  = (const float*)d_in[0];
    const float* k  = (const float*)d_in[1];
    const float* v  = (const float*)d_in[2];
    const int*   vl = (const int*)d_in[3];
    float* out = (float*)d_out;

    const size_t kvbytes = 2 * (size_t)NB * NK * ND * sizeof(unsigned short); // 16 MB
    if (ws_size >= kvbytes) {
        unsigned short* wk  = (unsigned short*)d_ws;
        unsigned short* wvt = wk + (size_t)NB * NK * ND;
        hipLaunchKernelGGL(prep_kv5, dim3(NTILE, NB), dim3(256), 0, stream, k, v, vl, wk, wvt);
        hipLaunchKernelGGL(attn_fused17, dim3((NQ / 64) * NB), dim3(256), 0, stream,
                           q, vl, wk, wvt, out);
    } else {
        hipLaunchKernelGGL(attn_fused, dim3(NQ / 64, NB), dim3(256), 0, stream,
                           q, k, v, vl, out);
    }
}

// Round 18
// 55.009 us; speedup vs baseline: 1.0877x; 1.0324x over previous
//
#include <hip/hip_runtime.h>

// Problem constants (reference: B=16, Q=2048, K=2048, D=128, fp32, NEG=-1e6)
constexpr int NB = 16;
constexpr int NQ = 2048;
constexpr int NK = 2048;
constexpr int ND = 128;
constexpr int KVBLK = 64;                 // kv per tile
constexpr int NTILE = NK / KVBLK;         // 32
constexpr int TILE_USH = KVBLK * ND;      // 8192 ushorts = 16KB per tile
// 1/sqrt(128) * log2(e): QK^T emits log2-domain scores; exp -> v_exp_f32 (2^x)
constexpr float SCALE2 = 0.12751744751442557f;

typedef __attribute__((ext_vector_type(4))) float f4;
typedef __attribute__((ext_vector_type(16))) float f32x16;
typedef __attribute__((ext_vector_type(8))) unsigned short us8;
typedef __attribute__((ext_vector_type(8))) __bf16 bf16x8;
typedef __attribute__((ext_vector_type(4))) unsigned int u32x4;

static __device__ __forceinline__ unsigned short f2bf(float f) {
    unsigned u = __builtin_bit_cast(unsigned, f);
    u += 0x7fffu + ((u >> 16) & 1u);
    return (unsigned short)(u >> 16);
}
static __device__ __forceinline__ f4 splat4(float x) { f4 r = {x,x,x,x}; return r; }

static __device__ __forceinline__ float fexp2(float x) {
    float r;
    asm("v_exp_f32 %0, %1" : "=v"(r) : "v"(x));
    return r;
}

static __device__ __forceinline__ void load_lds16(const unsigned short* g, unsigned short* l) {
    __builtin_amdgcn_global_load_lds(
        (const __attribute__((address_space(1))) void*)g,
        (__attribute__((address_space(3))) void*)l,
        16, 0, 0);
}

static __device__ __forceinline__ unsigned cvt_pk_bf16(float lo, float hi) {
    unsigned r;
    asm("v_cvt_pk_bf16_f32 %0, %1, %2" : "=v"(r) : "v"(lo), "v"(hi));
    return r;
}

// ---------------------------------------------------------------------------
// Prep: per (batch, kv-tile=64) write K and V in lane-linear 32x32-MFMA
// fragment order (verified R5-R17):
//  K  (kv,d): off = ((kv>>5)*8 + (d>>4))*512 + ((d>>3)&1)*256 + (kv&31)*8 + (d&7)
//  V  (kv,d): off = ((kv>>4)*4 + (d>>5))*512 + ((kv>>3)&1)*256 + (d&31)*8 + (kv&7)
// Early-exit for tiles beyond valid length (attn never reads them).
// grid (NTILE, NB), 256 threads
// ---------------------------------------------------------------------------
__global__ __launch_bounds__(256)
void prep_kv5(const float* __restrict__ kg, const float* __restrict__ vg,
              const int* __restrict__ vlen,
              unsigned short* __restrict__ wk, unsigned short* __restrict__ wvt)
{
    const int b   = blockIdx.y;
    const int t   = blockIdx.x;
    const int kv0 = t * KVBLK;

    {
        const int v = vlen[b];
        const int Leff = (v <= 0) ? NK : v;
        if (kv0 >= Leff) return;
    }

    const int t0  = threadIdx.x;

    __shared__ __align__(16) unsigned short vl[64 * 136];

    {
        const int kv = t0 >> 2;
        const int c  = t0 & 3;
        const float* gp = kg + (size_t)(b * NK + kv0 + kv) * ND + c * 32;
        unsigned short* ob = wk + (size_t)(b * NTILE + t) * TILE_USH;
        #pragma unroll
        for (int g = 0; g < 4; ++g) {
            f4 f0 = *(const f4*)(gp + g * 8);
            f4 f1 = *(const f4*)(gp + g * 8 + 4);
            us8 w;
            #pragma unroll
            for (int i = 0; i < 4; ++i) { w[i] = f2bf(f0[i]); w[i+4] = f2bf(f1[i]); }
            const int d0 = c * 32 + g * 8;
            const int f  = (kv >> 5) * 8 + (d0 >> 4);
            const int off = f * 512 + ((d0 >> 3) & 1) * 256 + (kv & 31) * 8;
            *(us8*)(ob + off) = w;
        }
    }
    {
        const int kv = t0 >> 2;
        const int d0 = (t0 & 3) * 32;
        const float* gp = vg + (size_t)(b * NK + kv0 + kv) * ND + d0;
        unsigned short* lb = &vl[kv * 136 + d0];
        #pragma unroll
        for (int g = 0; g < 4; ++g) {
            f4 f0 = *(const f4*)(gp + g * 8);
            f4 f1 = *(const f4*)(gp + g * 8 + 4);
            us8 w;
            #pragma unroll
            for (int i = 0; i < 4; ++i) { w[i] = f2bf(f0[i]); w[i+4] = f2bf(f1[i]); }
            *(us8*)(lb + g * 8) = w;
        }
    }
    __syncthreads();
    {
        unsigned short* ob = wvt + (size_t)(b * NTILE + t) * TILE_USH;
        #pragma unroll
        for (int iter = 0; iter < 4; ++iter) {
            const int cid = iter * 256 + t0;
            const int f   = cid >> 6;
            const int l   = cid & 63;
            const int kb  = (f >> 2) * 16 + (l >> 5) * 8;
            const int d   = (f & 3) * 32 + (l & 31);
            us8 w;
            #pragma unroll
            for (int j = 0; j < 8; ++j) w[j] = vl[(kb + j) * 136 + d];
            *(us8*)(ob + cid * 8) = w;
        }
    }
}

// ---------------------------------------------------------------------------
// Fused attention v18: R14 frame (256-thr blocks, QBLK=64, 2 KV-groups x
// 2 q-waves, complementary-rank batch pairing, log2 softmax) with:
//  - V fragments loaded DIRECT from global (L2-resident, wave-contiguous 1KB,
//    2nd wave's identical reads hit L1) -> no V DMA, no V ds_reads
//  - K double-buffered in the freed LDS (2 grp x 2 buf x 16KB = 64KB):
//    K-DMA issued at iteration top, covered by the WHOLE body
//  - ONE __syncthreads per iteration (was 2)
// ---------------------------------------------------------------------------
__global__ __launch_bounds__(256, 2)
void attn_fused18(const float* __restrict__ qg, const int* __restrict__ vlen,
                  const unsigned short* __restrict__ wk,
                  const unsigned short* __restrict__ wvt,
                  float* __restrict__ og)
{
    const int bid  = blockIdx.x;
    const int half = bid >> 8;      // 0: long ranks 0-7, 1: short ranks 15-8
    const int j    = bid & 255;
    const int rank = half ? (15 - (j & 7)) : (j & 7);
    const int qc   = j >> 3;        // 0..31
    const int q0   = qc * 64;

    // batch with this Leff-descending rank (ties by index)
    int b = 0;
    {
        int Ls[16];
        #pragma unroll
        for (int i = 0; i < 16; ++i) {
            const int v = vlen[i];
            Ls[i] = (v <= 0) ? NK : v;
        }
        #pragma unroll
        for (int bb = 0; bb < 16; ++bb) {
            int r = 0;
            #pragma unroll
            for (int cc = 0; cc < 16; ++cc)
                r += (Ls[cc] > Ls[bb] || (Ls[cc] == Ls[bb] && cc < bb)) ? 1 : 0;
            if (r == rank) b = bb;
        }
    }

    const int tid  = threadIdx.x;
    const int wid  = tid >> 6;
    const int grp  = wid >> 1;     // KV-split group 0/1 (tiles t%2==grp)
    const int qw   = wid & 1;      // q-chunk within block (32 rows each)
    const int lane = tid & 63;
    const int lq   = lane & 31;
    const int hi   = lane >> 5;

    const int L = vlen[b];
    const bool uniform = (L <= 0);
    const int Leff = uniform ? NK : L;
    const int ntiles = (Leff + KVBLK - 1) / KVBLK;
    const int ng    = (ntiles + 1 - grp) >> 1;
    const int niter = (ntiles + 1) >> 1;

    // K double-buffer: [group][buf][16KB] = 64 KB total
    __shared__ __align__(16) unsigned short kbuf[2][2][8192];

    // ---- Q fragments (B-operand), scaled by 1/sqrt(D)*log2(e)
    bf16x8 aq[8];
    {
        const float* qp = qg + (size_t)(b * NQ + q0 + qw * 32 + lq) * ND + hi * 8;
        #pragma unroll
        for (int c = 0; c < 8; ++c) {
            f4 f0 = *(const f4*)(qp + c * 16);
            f4 f1 = *(const f4*)(qp + c * 16 + 4);
            us8 u;
            #pragma unroll
            for (int i = 0; i < 4; ++i) {
                u[i]     = f2bf(f0[i] * SCALE2);
                u[i + 4] = f2bf(f1[i] * SCALE2);
            }
            aq[c] = __builtin_bit_cast(bf16x8, u);
        }
    }

    const unsigned short* kbg = wk  + (size_t)b * NTILE * TILE_USH;
    const unsigned short* vbg = wvt + (size_t)b * NTILE * TILE_USH;

    // K staging: each of the group's 2 waves DMAs 8KB (8 x 1KB)
    const int s_off = qw * 4096 + lane * 8;

    float m_r = -__builtin_inff();
    float l_r = 0.f;
    f32x16 accO[4];
    #pragma unroll
    for (int dc = 0; dc < 4; ++dc)
        #pragma unroll
        for (int r = 0; r < 16; ++r) accO[dc][r] = 0.f;

    // ---- prologue: stage K tile grp into buf 0
    if (grp < ntiles) {
        const unsigned short* src = kbg + (size_t)grp * TILE_USH + s_off;
        unsigned short* dst = &kbuf[grp][0][qw * 4096];
        #pragma unroll
        for (int jj = 0; jj < 8; ++jj) load_lds16(src + jj * 512, dst + jj * 512);
    }
    __syncthreads();

    for (int i = 0; i < niter; ++i) {
        const int tile = 2 * i + grp;
        const int buf  = i & 1;

        // ---- issue next K tile's DMA into the other buffer (top of body:
        // covered by the full QK+SM+PV; other buffer's reads finished last
        // iteration, fenced by the previous barrier)
        {
            const int tn = tile + 2;
            if (tn < ntiles) {
                const unsigned short* src = kbg + (size_t)tn * TILE_USH + s_off;
                unsigned short* dst = &kbuf[grp][buf ^ 1][qw * 4096];
                #pragma unroll
                for (int jj = 0; jj < 8; ++jj) load_lds16(src + jj * 512, dst + jj * 512);
            }
        }

        if (i < ng) {
            const int kv0 = tile * KVBLK;
            const unsigned short* kl = &kbuf[grp][buf][0];

            // ---- K frags -> regs, QK^T (swapped: S^T[64k x 32q], log2 dom)
            us8 kf[16];
            #pragma unroll
            for (int c = 0; c < 16; ++c)
                kf[c] = *(const us8*)&kl[c * 512 + lane * 8];
            f32x16 sA, sB;
            #pragma unroll
            for (int r = 0; r < 16; ++r) { sA[r] = 0.f; sB[r] = 0.f; }
            #pragma unroll
            for (int c = 0; c < 8; ++c) {
                sA = __builtin_amdgcn_mfma_f32_32x32x16_bf16(
                    __builtin_bit_cast(bf16x8, kf[c]), aq[c], sA, 0, 0, 0);
                sB = __builtin_amdgcn_mfma_f32_32x32x16_bf16(
                    __builtin_bit_cast(bf16x8, kf[8 + c]), aq[c], sB, 0, 0, 0);
            }
            __builtin_amdgcn_sched_barrier(0);   // VGPR peak control

            // ---- V frags DIRECT from global (L2/L1-resident, coalesced 1KB;
            // latency hidden under mask+softmax below)
            us8 vf[16];
            {
                const unsigned short* vsrc = vbg + (size_t)tile * TILE_USH + lane * 8;
                #pragma unroll
                for (int f = 0; f < 16; ++f)
                    vf[f] = *(const us8*)(vsrc + f * 512);
            }

            // ---- mask (rows = k)
            if (uniform) {
                #pragma unroll
                for (int r = 0; r < 16; ++r) { sA[r] = 0.f; sB[r] = 0.f; }
            } else {
                const int lim0 = L - kv0 - 4 * hi;
                const int lim1 = lim0 - 32;
                #pragma unroll
                for (int r = 0; r < 16; ++r) {
                    const int rc = (r & 3) + 8 * (r >> 2);
                    sA[r] = (rc >= lim0) ? -__builtin_inff() : sA[r];
                    sB[r] = (rc >= lim1) ? -__builtin_inff() : sB[r];
                }
            }

            // ---- in-register softmax for q = lq (log2 domain), 3-ary max
            float tt[11];
            #pragma unroll
            for (int g3 = 0; g3 < 5; ++g3)
                tt[g3] = fmaxf(fmaxf(sA[3 * g3], sA[3 * g3 + 1]), sA[3 * g3 + 2]);
            tt[5] = fmaxf(fmaxf(sA[15], sB[0]), sB[1]);
            #pragma unroll
            for (int g3 = 0; g3 < 4; ++g3)
                tt[6 + g3] = fmaxf(fmaxf(sB[3 * g3 + 2], sB[3 * g3 + 3]), sB[3 * g3 + 4]);
            tt[10] = fmaxf(sB[14], sB[15]);
            const float u0 = fmaxf(fmaxf(tt[0], tt[1]), tt[2]);
            const float u1 = fmaxf(fmaxf(tt[3], tt[4]), tt[5]);
            const float u2 = fmaxf(fmaxf(tt[6], tt[7]), tt[8]);
            const float u3 = fmaxf(tt[9], tt[10]);
            const float pm = fmaxf(fmaxf(u0, u1), fmaxf(u2, u3));
            float pmax = fmaxf(pm, __shfl_xor(pm, 32));

            // T13: rescale only when some q-row got a new max
            if (__any(pmax > m_r)) {
                const float mnew = fmaxf(m_r, pmax);
                const float sc = fexp2(m_r - mnew);
                m_r = mnew;
                l_r *= sc;
                #pragma unroll
                for (int r = 0; r < 16; ++r) {
                    const int src = ((r & 3) + 8 * (r >> 2) + 4 * hi) + (lane & 32);
                    const float scr = __shfl(sc, src);
                    accO[0][r] *= scr; accO[1][r] *= scr;
                    accO[2][r] *= scr; accO[3][r] *= scr;
                }
            }

            // ---- 2^x + row-sum
            float p0[16], p1[16];
            #pragma unroll
            for (int r = 0; r < 16; ++r) {
                p0[r] = fexp2(sA[r] - m_r);
                p1[r] = fexp2(sB[r] - m_r);
            }
            float sm[8];
            #pragma unroll
            for (int i2 = 0; i2 < 8; ++i2)
                sm[i2] = (p0[i2] + p0[i2 + 8]) + (p1[i2] + p1[i2 + 8]);
            #pragma unroll
            for (int i2 = 0; i2 < 4; ++i2) sm[i2] += sm[i2 + 4];
            float rsum = (sm[0] + sm[1]) + (sm[2] + sm[3]);
            rsum += __shfl_xor(rsum, 32);
            l_r += rsum;

            // ---- P -> bf16 packed words; half-exchange builds PV A-frags
            unsigned cw[16];
            #pragma unroll
            for (int i2 = 0; i2 < 8; ++i2) cw[i2] = cvt_pk_bf16(p0[2 * i2], p0[2 * i2 + 1]);
            #pragma unroll
            for (int i2 = 0; i2 < 8; ++i2) cw[8 + i2] = cvt_pk_bf16(p1[2 * i2], p1[2 * i2 + 1]);

            bf16x8 pa[4];
            #pragma unroll
            for (int ks = 0; ks < 4; ++ks) {
                const int a = 4 * ks;
                const unsigned u = hi ? cw[a]     : cw[a + 2];
                const unsigned v = hi ? cw[a + 1] : cw[a + 3];
                const unsigned up = __shfl_xor((int)u, 32);
                const unsigned vp = __shfl_xor((int)v, 32);
                u32x4 w;
                w[0] = hi ? up        : cw[a];
                w[1] = hi ? vp        : cw[a + 1];
                w[2] = hi ? cw[a + 2] : up;
                w[3] = hi ? cw[a + 3] : vp;
                pa[ks] = __builtin_bit_cast(bf16x8, w);
            }

            // ---- PV from regs
            #pragma unroll
            for (int dc = 0; dc < 4; ++dc) {
                #pragma unroll
                for (int ks = 0; ks < 4; ++ks) {
                    accO[dc] = __builtin_amdgcn_mfma_f32_32x32x16_bf16(
                        pa[ks], __builtin_bit_cast(bf16x8, vf[ks * 4 + dc]), accO[dc], 0, 0, 0);
                }
            }
        }

        // single barrier: drains this iteration's K-DMA (vmcnt 0, covered by
        // the body above) and fences buffer rotation
        __syncthreads();
    }

    // ---- merge epilogue: group1 -> LDS (32KB accO + m/l), group0 combines
    float* accb = (float*)&kbuf[0][0][0];
    float* mlb  = accb + 8192;            // 128 floats
    if (grp == 1) {
        #pragma unroll
        for (int dc = 0; dc < 4; ++dc) {
            #pragma unroll
            for (int q4 = 0; q4 < 4; ++q4) {
                f4 v;
                #pragma unroll
                for (int c = 0; c < 4; ++c) v[c] = accO[dc][q4 * 4 + c];
                *(f4*)&accb[(((qw * 16 + dc * 4 + q4) * 64) + lane) * 4] = v;
            }
        }
        if (hi == 0) {
            mlb[qw * 32 + lq]      = m_r;
            mlb[64 + qw * 32 + lq] = l_r;
        }
    }
    __syncthreads();
    if (grp == 0) {
        const float m1 = mlb[qw * 32 + lq];
        const float l1 = mlb[64 + qw * 32 + lq];
        const float m  = fmaxf(m_r, m1);
        const float a0 = fexp2(m_r - m), a1 = fexp2(m1 - m);
        const float linv = 1.0f / (a0 * l_r + a1 * l1);
        const float s0v = a0 * linv, s1v = a1 * linv;
        float* ob = og + (size_t)(b * NQ + q0 + qw * 32) * ND;
        #pragma unroll
        for (int dc = 0; dc < 4; ++dc) {
            #pragma unroll
            for (int q4 = 0; q4 < 4; ++q4) {
                f4 o1 = *(const f4*)&accb[(((qw * 16 + dc * 4 + q4) * 64) + lane) * 4];
                #pragma unroll
                for (int c = 0; c < 4; ++c) {
                    const int r = q4 * 4 + c;
                    const int row = c + 8 * q4 + 4 * hi;
                    const float s0r = __shfl(s0v, row + (lane & 32));
                    const float s1r = __shfl(s1v, row + (lane & 32));
                    ob[(size_t)row * ND + dc * 32 + lq] = accO[dc][r] * s0r + o1[c] * s1r;
                }
            }
        }
    }
}

// ---------------------------------------------------------------------------
// Fallback (R1 kernel): used only if ws_size < 16 MB
// ---------------------------------------------------------------------------
__global__ __launch_bounds__(256, 2)
void attn_fused(const float* __restrict__ qg, const float* __restrict__ kg,
                const float* __restrict__ vg, const int* __restrict__ vlen,
                float* __restrict__ og)
{
    const int b    = blockIdx.y;
    const int q0   = blockIdx.x * 64;
    const int tid  = threadIdx.x;
    const int wid  = tid >> 6;
    const int lane = tid & 63;
    const int lrow = lane & 15;
    const int lgrp = lane >> 4;
    constexpr float SCALE = 0.08838834764831844f;

    const int L = vlen[b];
    const bool uniform = (L <= 0);
    const int Leff = uniform ? NK : L;
    const int nt32 = (Leff + 31) / 32;

    __shared__ __align__(16) unsigned short kt[32 * 136];
    __shared__ __align__(16) unsigned short vt[128 * 40];
    __shared__ __align__(16) float pt[4][16 * 36];

    bf16x8 aqf[4];
    {
        const float* qp = qg + (size_t)(b * NQ + q0 + wid * 16 + lrow) * ND + lgrp * 8;
        #pragma unroll
        for (int c = 0; c < 4; ++c) {
            f4 f0 = *(const f4*)(qp + c * 32);
            f4 f1 = *(const f4*)(qp + c * 32 + 4);
            us8 u;
            #pragma unroll
            for (int i = 0; i < 4; ++i) {
                u[i]     = f2bf(f0[i] * SCALE);
                u[i + 4] = f2bf(f1[i] * SCALE);
            }
            aqf[c] = __builtin_bit_cast(bf16x8, u);
        }
    }

    float m_r[4], l_r[4];
    f4 accO[8];
    #pragma unroll
    for (int r = 0; r < 4; ++r) { m_r[r] = -__builtin_inff(); l_r[r] = 0.f; }
    #pragma unroll
    for (int dc = 0; dc < 8; ++dc) accO[dc] = splat4(0.f);

    for (int t = 0; t < nt32; ++t) {
        const int kv0 = t * 32;
        __syncthreads();
        {
            const int r  = tid >> 3;
            const int c0 = (tid & 7) * 16;
            const float* gp = kg + (size_t)(b * NK + kv0 + r) * ND + c0;
            f4 f0 = *(const f4*)(gp);
            f4 f1 = *(const f4*)(gp + 4);
            f4 f2 = *(const f4*)(gp + 8);
            f4 f3 = *(const f4*)(gp + 12);
            us8 w0, w1;
            #pragma unroll
            for (int i = 0; i < 4; ++i) {
                w0[i]     = f2bf(f0[i]);
                w0[i + 4] = f2bf(f1[i]);
                w1[i]     = f2bf(f2[i]);
                w1[i + 4] = f2bf(f3[i]);
            }
            unsigned short* dst = &kt[r * 136 + c0];
            *(us8*)(dst)     = w0;
            *(us8*)(dst + 8) = w1;
        }
        {
            const int d  = tid & 127;
            const int g2 = tid >> 7;
            const float* gp = vg + (size_t)(b * NK + kv0 + g2 * 16) * ND + d;
            us8 w0, w1;
            #pragma unroll
            for (int jj = 0; jj < 8; ++jj) {
                w0[jj] = f2bf(gp[(size_t)jj * ND]);
                w1[jj] = f2bf(gp[(size_t)(jj + 8) * ND]);
            }
            unsigned short* dst = &vt[d * 40 + g2 * 16];
            *(us8*)(dst)     = w0;
            *(us8*)(dst + 8) = w1;
        }
        __syncthreads();

        f4 s0 = splat4(0.f), s1 = splat4(0.f);
        #pragma unroll
        for (int c = 0; c < 4; ++c) {
            bf16x8 bk0 = __builtin_bit_cast(bf16x8,
                *(const us8*)&kt[lrow * 136 + c * 32 + lgrp * 8]);
            s0 = __builtin_amdgcn_mfma_f32_16x16x32_bf16(aqf[c], bk0, s0, 0, 0, 0);
            bf16x8 bk1 = __builtin_bit_cast(bf16x8,
                *(const us8*)&kt[(16 + lrow) * 136 + c * 32 + lgrp * 8]);
            s1 = __builtin_amdgcn_mfma_f32_16x16x32_bf16(aqf[c], bk1, s1, 0, 0, 0);
        }

        const int col0 = kv0 + lrow;
        if (uniform) {
            s0 = splat4(0.f);
            s1 = splat4(0.f);
        } else {
            if (col0 >= L)      s0 = splat4(-__builtin_inff());
            if (col0 + 16 >= L) s1 = splat4(-__builtin_inff());
        }

        float pm[4];
        #pragma unroll
        for (int r = 0; r < 4; ++r) pm[r] = fmaxf(s0[r], s1[r]);
        #pragma unroll
        for (int off = 8; off > 0; off >>= 1) {
            #pragma unroll
            for (int r = 0; r < 4; ++r)
                pm[r] = fmaxf(pm[r], __shfl_xor(pm[r], off));
        }
        float pr0[4], pr1[4], rs[4], sc[4];
        #pragma unroll
        for (int r = 0; r < 4; ++r) {
            float mn = fmaxf(m_r[r], pm[r]);
            sc[r]  = __expf(m_r[r] - mn);
            m_r[r] = mn;
            pr0[r] = __expf(s0[r] - mn);
            pr1[r] = __expf(s1[r] - mn);
            rs[r]  = pr0[r] + pr1[r];
        }
        #pragma unroll
        for (int off = 8; off > 0; off >>= 1) {
            #pragma unroll
            for (int r = 0; r < 4; ++r)
                rs[r] += __shfl_xor(rs[r], off);
        }
        #pragma unroll
        for (int r = 0; r < 4; ++r) l_r[r] = l_r[r] * sc[r] + rs[r];
        #pragma unroll
        for (int dc = 0; dc < 8; ++dc) {
            #pragma unroll
            for (int r = 0; r < 4; ++r) accO[dc][r] *= sc[r];
        }

        float* pw = pt[wid];
        #pragma unroll
        for (int r = 0; r < 4; ++r) {
            pw[(lgrp * 4 + r) * 36 + lrow]      = pr0[r];
            pw[(lgrp * 4 + r) * 36 + 16 + lrow] = pr1[r];
        }
        asm volatile("s_waitcnt lgkmcnt(0)" ::: "memory");
        f4 a0 = *(const f4*)&pw[lrow * 36 + lgrp * 8];
        f4 a1 = *(const f4*)&pw[lrow * 36 + lgrp * 8 + 4];
        us8 au;
        #pragma unroll
        for (int i = 0; i < 4; ++i) { au[i] = f2bf(a0[i]); au[i + 4] = f2bf(a1[i]); }
        bf16x8 ap = __builtin_bit_cast(bf16x8, au);

        #pragma unroll
        for (int dc = 0; dc < 8; ++dc) {
            bf16x8 bv = __builtin_bit_cast(bf16x8,
                *(const us8*)&vt[(dc * 16 + lrow) * 40 + lgrp * 8]);
            accO[dc] = __builtin_amdgcn_mfma_f32_16x16x32_bf16(ap, bv, accO[dc], 0, 0, 0);
        }
    }

    float inv[4];
    #pragma unroll
    for (int r = 0; r < 4; ++r) inv[r] = 1.0f / l_r[r];
    float* op = og + (size_t)(b * NQ + q0 + wid * 16) * ND;
    #pragma unroll
    for (int dc = 0; dc < 8; ++dc) {
        #pragma unroll
        for (int r = 0; r < 4; ++r)
            op[(lgrp * 4 + r) * ND + dc * 16 + lrow] = accO[dc][r] * inv[r];
    }
}

extern "C" void kernel_launch(void* const* d_in, const int* in_sizes, int n_in,
                              void* d_out, int out_size, void* d_ws, size_t ws_size,
                              hipStream_t stream) {
    (void)in_sizes; (void)n_in; (void)out_size;
    const float* q  = (const float*)d_in[0];
    const float* k  = (const float*)d_in[1];
    const float* v  = (const float*)d_in[2];
    const int*   vl = (const int*)d_in[3];
    float* out = (float*)d_out;

    const size_t kvbytes = 2 * (size_t)NB * NK * ND * sizeof(unsigned short); // 16 MB
    if (ws_size >= kvbytes) {
        unsigned short* wk  = (unsigned short*)d_ws;
        unsigned short* wvt = wk + (size_t)NB * NK * ND;
        hipLaunchKernelGGL(prep_kv5, dim3(NTILE, NB), dim3(256), 0, stream, k, v, vl, wk, wvt);
        hipLaunchKernelGGL(attn_fused18, dim3((NQ / 64) * NB), dim3(256), 0, stream,
                           q, vl, wk, wvt, out);
    } else {
        hipLaunchKernelGGL(attn_fused, dim3(NQ / 64, NB), dim3(256), 0, stream,
                           q, k, v, vl, out);
    }
}

// Round 19
// 51.883 us; speedup vs baseline: 1.1532x; 1.0602x over previous
//
#include <hip/hip_runtime.h>

// Problem constants (reference: B=16, Q=2048, K=2048, D=128, fp32, NEG=-1e6)
constexpr int NB = 16;
constexpr int NQ = 2048;
constexpr int NK = 2048;
constexpr int ND = 128;
constexpr int KVBLK = 64;                 // kv per tile
constexpr int NTILE = NK / KVBLK;         // 32
constexpr int TILE_USH = KVBLK * ND;      // 8192 ushorts = 16KB per tile
// 1/sqrt(128) * log2(e): QK^T emits log2-domain scores; exp -> v_exp_f32 (2^x)
constexpr float SCALE2 = 0.12751744751442557f;

typedef __attribute__((ext_vector_type(4))) float f4;
typedef __attribute__((ext_vector_type(16))) float f32x16;
typedef __attribute__((ext_vector_type(8))) unsigned short us8;
typedef __attribute__((ext_vector_type(8))) __bf16 bf16x8;
typedef __attribute__((ext_vector_type(4))) unsigned int u32x4;

static __device__ __forceinline__ unsigned short f2bf(float f) {
    unsigned u = __builtin_bit_cast(unsigned, f);
    u += 0x7fffu + ((u >> 16) & 1u);
    return (unsigned short)(u >> 16);
}
static __device__ __forceinline__ f4 splat4(float x) { f4 r = {x,x,x,x}; return r; }

static __device__ __forceinline__ float fexp2(float x) {
    float r;
    asm("v_exp_f32 %0, %1" : "=v"(r) : "v"(x));
    return r;
}

static __device__ __forceinline__ void load_lds16(const unsigned short* g, unsigned short* l) {
    __builtin_amdgcn_global_load_lds(
        (const __attribute__((address_space(1))) void*)g,
        (__attribute__((address_space(3))) void*)l,
        16, 0, 0);
}

static __device__ __forceinline__ unsigned cvt_pk_bf16(float lo, float hi) {
    unsigned r;
    asm("v_cvt_pk_bf16_f32 %0, %1, %2" : "=v"(r) : "v"(lo), "v"(hi));
    return r;
}

// ---------------------------------------------------------------------------
// Prep: per (batch, kv-tile=64) write K and V in lane-linear 32x32-MFMA
// fragment order (verified R5-R18):
//  K  (kv,d): off = ((kv>>5)*8 + (d>>4))*512 + ((d>>3)&1)*256 + (kv&31)*8 + (d&7)
//  V  (kv,d): off = ((kv>>4)*4 + (d>>5))*512 + ((kv>>3)&1)*256 + (d&31)*8 + (kv&7)
// Early-exit for tiles beyond valid length (attn never reads them).
// grid (NTILE, NB), 256 threads
// ---------------------------------------------------------------------------
__global__ __launch_bounds__(256)
void prep_kv5(const float* __restrict__ kg, const float* __restrict__ vg,
              const int* __restrict__ vlen,
              unsigned short* __restrict__ wk, unsigned short* __restrict__ wvt)
{
    const int b   = blockIdx.y;
    const int t   = blockIdx.x;
    const int kv0 = t * KVBLK;

    {
        const int v = vlen[b];
        const int Leff = (v <= 0) ? NK : v;
        if (kv0 >= Leff) return;
    }

    const int t0  = threadIdx.x;

    __shared__ __align__(16) unsigned short vl[64 * 136];

    {
        const int kv = t0 >> 2;
        const int c  = t0 & 3;
        const float* gp = kg + (size_t)(b * NK + kv0 + kv) * ND + c * 32;
        unsigned short* ob = wk + (size_t)(b * NTILE + t) * TILE_USH;
        #pragma unroll
        for (int g = 0; g < 4; ++g) {
            f4 f0 = *(const f4*)(gp + g * 8);
            f4 f1 = *(const f4*)(gp + g * 8 + 4);
            us8 w;
            #pragma unroll
            for (int i = 0; i < 4; ++i) { w[i] = f2bf(f0[i]); w[i+4] = f2bf(f1[i]); }
            const int d0 = c * 32 + g * 8;
            const int f  = (kv >> 5) * 8 + (d0 >> 4);
            const int off = f * 512 + ((d0 >> 3) & 1) * 256 + (kv & 31) * 8;
            *(us8*)(ob + off) = w;
        }
    }
    {
        const int kv = t0 >> 2;
        const int d0 = (t0 & 3) * 32;
        const float* gp = vg + (size_t)(b * NK + kv0 + kv) * ND + d0;
        unsigned short* lb = &vl[kv * 136 + d0];
        #pragma unroll
        for (int g = 0; g < 4; ++g) {
            f4 f0 = *(const f4*)(gp + g * 8);
            f4 f1 = *(const f4*)(gp + g * 8 + 4);
            us8 w;
            #pragma unroll
            for (int i = 0; i < 4; ++i) { w[i] = f2bf(f0[i]); w[i+4] = f2bf(f1[i]); }
            *(us8*)(lb + g * 8) = w;
        }
    }
    __syncthreads();
    {
        unsigned short* ob = wvt + (size_t)(b * NTILE + t) * TILE_USH;
        #pragma unroll
        for (int iter = 0; iter < 4; ++iter) {
            const int cid = iter * 256 + t0;
            const int f   = cid >> 6;
            const int l   = cid & 63;
            const int kb  = (f >> 2) * 16 + (l >> 5) * 8;
            const int d   = (f & 3) * 32 + (l & 31);
            us8 w;
            #pragma unroll
            for (int j = 0; j < 8; ++j) w[j] = vl[(kb + j) * 136 + d];
            *(us8*)(ob + cid * 8) = w;
        }
    }
}

// ---------------------------------------------------------------------------
// Fused attention v19: ZERO-BARRIER free-running waves.
// 128-thr blocks (2 waves = 2 KV-groups over the SAME 32 q-rows), grid 1024,
// 4 independent blocks/CU (8 waves/CU, never phase-locked). K and V both
// loaded direct from global (lane-linear fragment layout, L2-resident by XCD
// affinity). No LDS, no __syncthreads in the loop; 2-wave merge at the end.
// Complementary-rank pairing: CU's 4 blocks carry ranks {r,15-r,r,15-r}.
// ---------------------------------------------------------------------------
__global__ __launch_bounds__(128, 2)
void attn_fused19(const float* __restrict__ qg, const int* __restrict__ vlen,
                  const unsigned short* __restrict__ wk,
                  const unsigned short* __restrict__ wvt,
                  float* __restrict__ og)
{
    const int bid     = blockIdx.x;
    const int quarter = bid >> 8;       // 0..3
    const int j       = bid & 255;
    const int slot    = j & 7;          // XCD slot
    const int rank    = (quarter & 1) ? (15 - slot) : slot;
    const int qc      = (j >> 3) + ((quarter >> 1) << 5);   // 0..63
    const int q0      = qc * 32;

    // batch with this Leff-descending rank (ties by index)
    int b = 0;
    {
        int Ls[16];
        #pragma unroll
        for (int i = 0; i < 16; ++i) {
            const int v = vlen[i];
            Ls[i] = (v <= 0) ? NK : v;
        }
        #pragma unroll
        for (int bb = 0; bb < 16; ++bb) {
            int r = 0;
            #pragma unroll
            for (int cc = 0; cc < 16; ++cc)
                r += (Ls[cc] > Ls[bb] || (Ls[cc] == Ls[bb] && cc < bb)) ? 1 : 0;
            if (r == rank) b = bb;
        }
    }

    const int tid  = threadIdx.x;
    const int grp  = tid >> 6;     // KV group 0/1 (tiles t%2==grp)
    const int lane = tid & 63;
    const int lq   = lane & 31;
    const int hi   = lane >> 5;

    const int L = vlen[b];
    const bool uniform = (L <= 0);
    const int Leff = uniform ? NK : L;
    const int ntiles = (Leff + KVBLK - 1) / KVBLK;
    const int ng = (ntiles > grp) ? ((ntiles - grp + 1) >> 1) : 0;

    // merge-only LDS: 32 rows x 128 d fp32 (16KB) + m/l (256B)
    __shared__ __align__(16) float accb[32 * 128];
    __shared__ float mlb[64];

    // ---- Q fragments (B-operand), scaled by 1/sqrt(D)*log2(e)
    bf16x8 aq[8];
    {
        const float* qp = qg + (size_t)(b * NQ + q0 + lq) * ND + hi * 8;
        #pragma unroll
        for (int c = 0; c < 8; ++c) {
            f4 f0 = *(const f4*)(qp + c * 16);
            f4 f1 = *(const f4*)(qp + c * 16 + 4);
            us8 u;
            #pragma unroll
            for (int i = 0; i < 4; ++i) {
                u[i]     = f2bf(f0[i] * SCALE2);
                u[i + 4] = f2bf(f1[i] * SCALE2);
            }
            aq[c] = __builtin_bit_cast(bf16x8, u);
        }
    }

    const unsigned short* kbg = wk  + (size_t)b * NTILE * TILE_USH;
    const unsigned short* vbg = wvt + (size_t)b * NTILE * TILE_USH;

    float m_r = -1e30f;    // finite sentinel: empty group merges NaN-free
    float l_r = 0.f;
    f32x16 accO[4];
    #pragma unroll
    for (int dc = 0; dc < 4; ++dc)
        #pragma unroll
        for (int r = 0; r < 16; ++r) accO[dc][r] = 0.f;

    // ---- free-running KV loop: no barriers, no LDS
    for (int i = 0; i < ng; ++i) {
        const int tile = 2 * i + grp;
        const int kv0  = tile * KVBLK;

        // ---- K frags direct from global (wave-contiguous 1KB, L2-resident)
        us8 kf[16];
        {
            const unsigned short* ksrc = kbg + (size_t)tile * TILE_USH + lane * 8;
            #pragma unroll
            for (int c = 0; c < 16; ++c)
                kf[c] = *(const us8*)(ksrc + c * 512);
        }
        f32x16 sA, sB;
        #pragma unroll
        for (int r = 0; r < 16; ++r) { sA[r] = 0.f; sB[r] = 0.f; }
        #pragma unroll
        for (int c = 0; c < 8; ++c) {
            sA = __builtin_amdgcn_mfma_f32_32x32x16_bf16(
                __builtin_bit_cast(bf16x8, kf[c]), aq[c], sA, 0, 0, 0);
            sB = __builtin_amdgcn_mfma_f32_32x32x16_bf16(
                __builtin_bit_cast(bf16x8, kf[8 + c]), aq[c], sB, 0, 0, 0);
        }
        __builtin_amdgcn_sched_barrier(0);   // VGPR peak control

        // ---- V frags direct from global; latency hidden under softmax
        us8 vf[16];
        {
            const unsigned short* vsrc = vbg + (size_t)tile * TILE_USH + lane * 8;
            #pragma unroll
            for (int f = 0; f < 16; ++f)
                vf[f] = *(const us8*)(vsrc + f * 512);
        }

        // ---- mask (rows = k)
        if (uniform) {
            #pragma unroll
            for (int r = 0; r < 16; ++r) { sA[r] = 0.f; sB[r] = 0.f; }
        } else {
            const int lim0 = L - kv0 - 4 * hi;
            const int lim1 = lim0 - 32;
            #pragma unroll
            for (int r = 0; r < 16; ++r) {
                const int rc = (r & 3) + 8 * (r >> 2);
                sA[r] = (rc >= lim0) ? -__builtin_inff() : sA[r];
                sB[r] = (rc >= lim1) ? -__builtin_inff() : sB[r];
            }
        }

        // ---- in-register softmax for q = lq (log2 domain), 3-ary max
        float tt[11];
        #pragma unroll
        for (int g3 = 0; g3 < 5; ++g3)
            tt[g3] = fmaxf(fmaxf(sA[3 * g3], sA[3 * g3 + 1]), sA[3 * g3 + 2]);
        tt[5] = fmaxf(fmaxf(sA[15], sB[0]), sB[1]);
        #pragma unroll
        for (int g3 = 0; g3 < 4; ++g3)
            tt[6 + g3] = fmaxf(fmaxf(sB[3 * g3 + 2], sB[3 * g3 + 3]), sB[3 * g3 + 4]);
        tt[10] = fmaxf(sB[14], sB[15]);
        const float u0 = fmaxf(fmaxf(tt[0], tt[1]), tt[2]);
        const float u1 = fmaxf(fmaxf(tt[3], tt[4]), tt[5]);
        const float u2 = fmaxf(fmaxf(tt[6], tt[7]), tt[8]);
        const float u3 = fmaxf(tt[9], tt[10]);
        const float pm = fmaxf(fmaxf(u0, u1), fmaxf(u2, u3));
        float pmax = fmaxf(pm, __shfl_xor(pm, 32));

        // T13: rescale only when some q-row got a new max
        if (__any(pmax > m_r)) {
            const float mnew = fmaxf(m_r, pmax);
            const float sc = fexp2(m_r - mnew);
            m_r = mnew;
            l_r *= sc;
            #pragma unroll
            for (int r = 0; r < 16; ++r) {
                const int src = ((r & 3) + 8 * (r >> 2) + 4 * hi) + (lane & 32);
                const float scr = __shfl(sc, src);
                accO[0][r] *= scr; accO[1][r] *= scr;
                accO[2][r] *= scr; accO[3][r] *= scr;
            }
        }

        // ---- 2^x + row-sum
        float p0[16], p1[16];
        #pragma unroll
        for (int r = 0; r < 16; ++r) {
            p0[r] = fexp2(sA[r] - m_r);
            p1[r] = fexp2(sB[r] - m_r);
        }
        float sm[8];
        #pragma unroll
        for (int i2 = 0; i2 < 8; ++i2)
            sm[i2] = (p0[i2] + p0[i2 + 8]) + (p1[i2] + p1[i2 + 8]);
        #pragma unroll
        for (int i2 = 0; i2 < 4; ++i2) sm[i2] += sm[i2 + 4];
        float rsum = (sm[0] + sm[1]) + (sm[2] + sm[3]);
        rsum += __shfl_xor(rsum, 32);
        l_r += rsum;

        // ---- P -> bf16 packed words; half-exchange builds PV A-frags
        unsigned cw[16];
        #pragma unroll
        for (int i2 = 0; i2 < 8; ++i2) cw[i2] = cvt_pk_bf16(p0[2 * i2], p0[2 * i2 + 1]);
        #pragma unroll
        for (int i2 = 0; i2 < 8; ++i2) cw[8 + i2] = cvt_pk_bf16(p1[2 * i2], p1[2 * i2 + 1]);

        bf16x8 pa[4];
        #pragma unroll
        for (int ks = 0; ks < 4; ++ks) {
            const int a = 4 * ks;
            const unsigned u = hi ? cw[a]     : cw[a + 2];
            const unsigned v = hi ? cw[a + 1] : cw[a + 3];
            const unsigned up = __shfl_xor((int)u, 32);
            const unsigned vp = __shfl_xor((int)v, 32);
            u32x4 w;
            w[0] = hi ? up        : cw[a];
            w[1] = hi ? vp        : cw[a + 1];
            w[2] = hi ? cw[a + 2] : up;
            w[3] = hi ? cw[a + 3] : vp;
            pa[ks] = __builtin_bit_cast(bf16x8, w);
        }

        // ---- PV from regs
        #pragma unroll
        for (int dc = 0; dc < 4; ++dc) {
            #pragma unroll
            for (int ks = 0; ks < 4; ++ks) {
                accO[dc] = __builtin_amdgcn_mfma_f32_32x32x16_bf16(
                    pa[ks], __builtin_bit_cast(bf16x8, vf[ks * 4 + dc]), accO[dc], 0, 0, 0);
            }
        }
    }

    // ---- 2-wave merge epilogue: group1 -> LDS, group0 combines + stores
    if (grp == 1) {
        #pragma unroll
        for (int dc = 0; dc < 4; ++dc) {
            #pragma unroll
            for (int q4 = 0; q4 < 4; ++q4) {
                f4 v;
                #pragma unroll
                for (int c = 0; c < 4; ++c) v[c] = accO[dc][q4 * 4 + c];
                *(f4*)&accb[(((dc * 4 + q4) * 64) + lane) * 4] = v;
            }
        }
        if (hi == 0) {
            mlb[lq]      = m_r;
            mlb[32 + lq] = l_r;
        }
    }
    __syncthreads();
    if (grp == 0) {
        const float m1 = mlb[lq];
        const float l1 = mlb[32 + lq];
        const float m  = fmaxf(m_r, m1);
        const float a0 = fexp2(m_r - m), a1 = fexp2(m1 - m);
        const float linv = 1.0f / (a0 * l_r + a1 * l1);
        const float s0v = a0 * linv, s1v = a1 * linv;
        float* ob = og + (size_t)(b * NQ + q0) * ND;
        #pragma unroll
        for (int dc = 0; dc < 4; ++dc) {
            #pragma unroll
            for (int q4 = 0; q4 < 4; ++q4) {
                f4 o1 = *(const f4*)&accb[(((dc * 4 + q4) * 64) + lane) * 4];
                #pragma unroll
                for (int c = 0; c < 4; ++c) {
                    const int r = q4 * 4 + c;
                    const int row = c + 8 * q4 + 4 * hi;
                    const float s0r = __shfl(s0v, row + (lane & 32));
                    const float s1r = __shfl(s1v, row + (lane & 32));
                    ob[(size_t)row * ND + dc * 32 + lq] = accO[dc][r] * s0r + o1[c] * s1r;
                }
            }
        }
    }
}

// ---------------------------------------------------------------------------
// Fallback (R1 kernel): used only if ws_size < 16 MB
// ---------------------------------------------------------------------------
__global__ __launch_bounds__(256, 2)
void attn_fused(const float* __restrict__ qg, const float* __restrict__ kg,
                const float* __restrict__ vg, const int* __restrict__ vlen,
                float* __restrict__ og)
{
    const int b    = blockIdx.y;
    const int q0   = blockIdx.x * 64;
    const int tid  = threadIdx.x;
    const int wid  = tid >> 6;
    const int lane = tid & 63;
    const int lrow = lane & 15;
    const int lgrp = lane >> 4;
    constexpr float SCALE = 0.08838834764831844f;

    const int L = vlen[b];
    const bool uniform = (L <= 0);
    const int Leff = uniform ? NK : L;
    const int nt32 = (Leff + 31) / 32;

    __shared__ __align__(16) unsigned short kt[32 * 136];
    __shared__ __align__(16) unsigned short vt[128 * 40];
    __shared__ __align__(16) float pt[4][16 * 36];

    bf16x8 aqf[4];
    {
        const float* qp = qg + (size_t)(b * NQ + q0 + wid * 16 + lrow) * ND + lgrp * 8;
        #pragma unroll
        for (int c = 0; c < 4; ++c) {
            f4 f0 = *(const f4*)(qp + c * 32);
            f4 f1 = *(const f4*)(qp + c * 32 + 4);
            us8 u;
            #pragma unroll
            for (int i = 0; i < 4; ++i) {
                u[i]     = f2bf(f0[i] * SCALE);
                u[i + 4] = f2bf(f1[i] * SCALE);
            }
            aqf[c] = __builtin_bit_cast(bf16x8, u);
        }
    }

    float m_r[4], l_r[4];
    f4 accO[8];
    #pragma unroll
    for (int r = 0; r < 4; ++r) { m_r[r] = -__builtin_inff(); l_r[r] = 0.f; }
    #pragma unroll
    for (int dc = 0; dc < 8; ++dc) accO[dc] = splat4(0.f);

    for (int t = 0; t < nt32; ++t) {
        const int kv0 = t * 32;
        __syncthreads();
        {
            const int r  = tid >> 3;
            const int c0 = (tid & 7) * 16;
            const float* gp = kg + (size_t)(b * NK + kv0 + r) * ND + c0;
            f4 f0 = *(const f4*)(gp);
            f4 f1 = *(const f4*)(gp + 4);
            f4 f2 = *(const f4*)(gp + 8);
            f4 f3 = *(const f4*)(gp + 12);
            us8 w0, w1;
            #pragma unroll
            for (int i = 0; i < 4; ++i) {
                w0[i]     = f2bf(f0[i]);
                w0[i + 4] = f2bf(f1[i]);
                w1[i]     = f2bf(f2[i]);
                w1[i + 4] = f2bf(f3[i]);
            }
            unsigned short* dst = &kt[r * 136 + c0];
            *(us8*)(dst)     = w0;
            *(us8*)(dst + 8) = w1;
        }
        {
            const int d  = tid & 127;
            const int g2 = tid >> 7;
            const float* gp = vg + (size_t)(b * NK + kv0 + g2 * 16) * ND + d;
            us8 w0, w1;
            #pragma unroll
            for (int jj = 0; jj < 8; ++jj) {
                w0[jj] = f2bf(gp[(size_t)jj * ND]);
                w1[jj] = f2bf(gp[(size_t)(jj + 8) * ND]);
            }
            unsigned short* dst = &vt[d * 40 + g2 * 16];
            *(us8*)(dst)     = w0;
            *(us8*)(dst + 8) = w1;
        }
        __syncthreads();

        f4 s0 = splat4(0.f), s1 = splat4(0.f);
        #pragma unroll
        for (int c = 0; c < 4; ++c) {
            bf16x8 bk0 = __builtin_bit_cast(bf16x8,
                *(const us8*)&kt[lrow * 136 + c * 32 + lgrp * 8]);
            s0 = __builtin_amdgcn_mfma_f32_16x16x32_bf16(aqf[c], bk0, s0, 0, 0, 0);
            bf16x8 bk1 = __builtin_bit_cast(bf16x8,
                *(const us8*)&kt[(16 + lrow) * 136 + c * 32 + lgrp * 8]);
            s1 = __builtin_amdgcn_mfma_f32_16x16x32_bf16(aqf[c], bk1, s1, 0, 0, 0);
        }

        const int col0 = kv0 + lrow;
        if (uniform) {
            s0 = splat4(0.f);
            s1 = splat4(0.f);
        } else {
            if (col0 >= L)      s0 = splat4(-__builtin_inff());
            if (col0 + 16 >= L) s1 = splat4(-__builtin_inff());
        }

        float pm[4];
        #pragma unroll
        for (int r = 0; r < 4; ++r) pm[r] = fmaxf(s0[r], s1[r]);
        #pragma unroll
        for (int off = 8; off > 0; off >>= 1) {
            #pragma unroll
            for (int r = 0; r < 4; ++r)
                pm[r] = fmaxf(pm[r], __shfl_xor(pm[r], off));
        }
        float pr0[4], pr1[4], rs[4], sc[4];
        #pragma unroll
        for (int r = 0; r < 4; ++r) {
            float mn = fmaxf(m_r[r], pm[r]);
            sc[r]  = __expf(m_r[r] - mn);
            m_r[r] = mn;
            pr0[r] = __expf(s0[r] - mn);
            pr1[r] = __expf(s1[r] - mn);
            rs[r]  = pr0[r] + pr1[r];
        }
        #pragma unroll
        for (int off = 8; off > 0; off >>= 1) {
            #pragma unroll
            for (int r = 0; r < 4; ++r)
                rs[r] += __shfl_xor(rs[r], off);
        }
        #pragma unroll
        for (int r = 0; r < 4; ++r) l_r[r] = l_r[r] * sc[r] + rs[r];
        #pragma unroll
        for (int dc = 0; dc < 8; ++dc) {
            #pragma unroll
            for (int r = 0; r < 4; ++r) accO[dc][r] *= sc[r];
        }

        float* pw = pt[wid];
        #pragma unroll
        for (int r = 0; r < 4; ++r) {
            pw[(lgrp * 4 + r) * 36 + lrow]      = pr0[r];
            pw[(lgrp * 4 + r) * 36 + 16 + lrow] = pr1[r];
        }
        asm volatile("s_waitcnt lgkmcnt(0)" ::: "memory");
        f4 a0 = *(const f4*)&pw[lrow * 36 + lgrp * 8];
        f4 a1 = *(const f4*)&pw[lrow * 36 + lgrp * 8 + 4];
        us8 au;
        #pragma unroll
        for (int i = 0; i < 4; ++i) { au[i] = f2bf(a0[i]); au[i + 4] = f2bf(a1[i]); }
        bf16x8 ap = __builtin_bit_cast(bf16x8, au);

        #pragma unroll
        for (int dc = 0; dc < 8; ++dc) {
            bf16x8 bv = __builtin_bit_cast(bf16x8,
                *(const us8*)&vt[(dc * 16 + lrow) * 40 + lgrp * 8]);
            accO[dc] = __builtin_amdgcn_mfma_f32_16x16x32_bf16(ap, bv, accO[dc], 0, 0, 0);
        }
    }

    float inv[4];
    #pragma unroll
    for (int r = 0; r < 4; ++r) inv[r] = 1.0f / l_r[r];
    float* op = og + (size_t)(b * NQ + q0 + wid * 16) * ND;
    #pragma unroll
    for (int dc = 0; dc < 8; ++dc) {
        #pragma unroll
        for (int r = 0; r < 4; ++r)
            op[(lgrp * 4 + r) * ND + dc * 16 + lrow] = accO[dc][r] * inv[r];
    }
}

extern "C" void kernel_launch(void* const* d_in, const int* in_sizes, int n_in,
                              void* d_out, int out_size, void* d_ws, size_t ws_size,
                              hipStream_t stream) {
    (void)in_sizes; (void)n_in; (void)out_size;
    const float* q  = (const float*)d_in[0];
    const float* k  = (const float*)d_in[1];
    const float* v  = (const float*)d_in[2];
    const int*   vl = (const int*)d_in[3];
    float* out = (float*)d_out;

    const size_t kvbytes = 2 * (size_t)NB * NK * ND * sizeof(unsigned short); // 16 MB
    if (ws_size >= kvbytes) {
        unsigned short* wk  = (unsigned short*)d_ws;
        unsigned short* wvt = wk + (size_t)NB * NK * ND;
        hipLaunchKernelGGL(prep_kv5, dim3(NTILE, NB), dim3(256), 0, stream, k, v, vl, wk, wvt);
        hipLaunchKernelGGL(attn_fused19, dim3((NQ / 32) * NB), dim3(128), 0, stream,
                           q, vl, wk, wvt, out);
    } else {
        hipLaunchKernelGGL(attn_fused, dim3(NQ / 64, NB), dim3(256), 0, stream,
                           q, k, v, vl, out);
    }
}